// Round 1
// baseline (307.094 us; speedup 1.0000x reference)
//
#include <hip/hip_runtime.h>
#include <stdint.h>

#define B_ 4
#define S_ 2048
#define D_ 512
#define H_ 8
#define FFN_ 2048
#define M_ (B_*S_)

typedef unsigned short u16;
typedef __attribute__((ext_vector_type(8))) __bf16 bf16x8;
typedef __attribute__((ext_vector_type(8))) u16 u16x8;
typedef __attribute__((ext_vector_type(4))) u16 u16x4;
typedef __attribute__((ext_vector_type(4))) float f32x4;

__device__ __forceinline__ u16 f2bf(float f) {
  uint32_t u = __builtin_bit_cast(uint32_t, f);
  u += 0x7FFFu + ((u >> 16) & 1u);
  return (u16)(u >> 16);
}
__device__ __forceinline__ bf16x8 ldfrag(const u16* p) {
  return __builtin_bit_cast(bf16x8, *(const u16x8*)p);
}
__device__ __forceinline__ void gld16(const void* g, void* l) {
  __builtin_amdgcn_global_load_lds(
      (const __attribute__((address_space(1))) void*)g,
      (__attribute__((address_space(3))) void*)l, 16, 0, 0);
}
__device__ __forceinline__ void bar() { asm volatile("s_barrier" ::: "memory"); }
// counted vmcnt fused with barrier: keeps N oldest-newer loads in flight
template <int N>
__device__ __forceinline__ void vm_bar() {
  if constexpr (N == 0) asm volatile("s_waitcnt vmcnt(0)\n\ts_barrier" ::: "memory");
  else                  asm volatile("s_waitcnt vmcnt(6)\n\ts_barrier" ::: "memory");
}
// one C-quadrant x K=64: 4 mfrag x 2 nfrag x 2 kslice = 16 MFMA under setprio
__device__ __forceinline__ void mm16(const bf16x8 (&aF)[4][2],
                                     const bf16x8 (&bF)[2][2],
                                     f32x4 (&ac)[4][2]) {
  __builtin_amdgcn_s_setprio(1);
#pragma unroll
  for (int mf = 0; mf < 4; mf++)
#pragma unroll
    for (int nf = 0; nf < 2; nf++)
#pragma unroll
      for (int ks = 0; ks < 2; ks++)
        ac[mf][nf] = __builtin_amdgcn_mfma_f32_16x16x32_bf16(
            aF[mf][ks], bF[nf][ks], ac[mf][nf], 0, 0, 0);
  __builtin_amdgcn_s_setprio(0);
}

// ---------------- merged weight prep: all transposes + bias concat --------
__global__ __launch_bounds__(256)
void prep(const float* __restrict__ wq, const float* __restrict__ wk,
          const float* __restrict__ wv, const float* __restrict__ w1,
          const float* __restrict__ w2, const float* __restrict__ bq,
          const float* __restrict__ bk, const float* __restrict__ bv,
          u16* __restrict__ wqkvt, u16* __restrict__ w1t,
          u16* __restrict__ w2t, float* __restrict__ bqkv) {
  int id = blockIdx.x, tid = threadIdx.x;
  if (id >= 2816) {
    int i = (id - 2816) * 256 + tid;
    bqkv[i] = i < 512 ? bq[i] : (i < 1024 ? bk[i - 512] : bv[i - 1024]);
    return;
  }
  __shared__ float t[32][33];
  const float* W; u16* dst; int K, N, bx, by;
  if (id < 768) {
    int z = id >> 8, r = id & 255;
    W = z == 0 ? wq : (z == 1 ? wk : wv);
    dst = wqkvt + (size_t)z * 512 * 512; K = 512; N = 512;
    bx = r & 15; by = r >> 4;
  } else if (id < 1792) {
    int r = id - 768; W = w1; dst = w1t; K = 512; N = 2048;
    bx = r & 63; by = r >> 6;
  } else {
    int r = id - 1792; W = w2; dst = w2t; K = 2048; N = 512;
    bx = r & 15; by = r >> 4;
  }
  int n0 = bx * 32, k0 = by * 32, x = tid & 31, y = tid >> 5;
#pragma unroll
  for (int r = 0; r < 4; r++) t[y + 8*r][x] = W[(size_t)(k0 + y + 8*r) * N + n0 + x];
  __syncthreads();
#pragma unroll
  for (int r = 0; r < 4; r++) dst[(size_t)(n0 + y + 8*r) * K + k0 + x] = f2bf(t[x][y + 8*r]);
}

// ---------------- layernorm over rows of 512 ------------------------------
// NX = number of bf16 partial arrays to add to x (split-K combine fused)
template <bool OUT32, bool OUT16, int NX>
__global__ __launch_bounds__(128)
void ln_k(const float* __restrict__ x, const float* __restrict__ g,
          const float* __restrict__ bta, float* __restrict__ y32,
          u16* __restrict__ y16, const u16* __restrict__ p1,
          const u16* __restrict__ p2, const u16* __restrict__ p3) {
  int row = blockIdx.x;
  int t = threadIdx.x;
  const float* xr = x + (size_t)row * 512;
  f32x4 v = *(const f32x4*)(xr + t * 4);
  if constexpr (NX >= 1) {
    u16x4 a = *(const u16x4*)(p1 + (size_t)row * 512 + t * 4);
#pragma unroll
    for (int j = 0; j < 4; j++) v[j] += __builtin_bit_cast(float, (uint32_t)a[j] << 16);
  }
  if constexpr (NX >= 2) {
    u16x4 a = *(const u16x4*)(p2 + (size_t)row * 512 + t * 4);
#pragma unroll
    for (int j = 0; j < 4; j++) v[j] += __builtin_bit_cast(float, (uint32_t)a[j] << 16);
  }
  if constexpr (NX >= 3) {
    u16x4 a = *(const u16x4*)(p3 + (size_t)row * 512 + t * 4);
#pragma unroll
    for (int j = 0; j < 4; j++) v[j] += __builtin_bit_cast(float, (uint32_t)a[j] << 16);
  }
  float s = v.x + v.y + v.z + v.w;
  float s2 = v.x*v.x + v.y*v.y + v.z*v.z + v.w*v.w;
#pragma unroll
  for (int m = 32; m; m >>= 1) { s += __shfl_xor(s, m); s2 += __shfl_xor(s2, m); }
  __shared__ float p[4];
  int wv = t >> 6;
  if ((t & 63) == 0) { p[wv] = s; p[2 + wv] = s2; }
  __syncthreads();
  s = p[0] + p[1]; s2 = p[2] + p[3];
  float mean = s * (1.f / 512.f);
  float var = s2 * (1.f / 512.f) - mean * mean;
  float rs = rsqrtf(var + 1e-5f);
#pragma unroll
  for (int j = 0; j < 4; j++) {
    float o = (v[j] - mean) * rs * g[t*4 + j] + bta[t*4 + j];
    if constexpr (OUT32) y32[(size_t)row * 512 + t*4 + j] = o;
    if constexpr (OUT16) y16[(size_t)row * 512 + t*4 + j] = f2bf(o);
  }
}

// ---------------- GEMM: 8-phase 256x256 template (T2+T3+T4+T5) -----------
// C[M,N] = A[M,K](bf16) @ Bt[N,K]^T + bias. 512 thr / 8 waves (2M x 4N per
// quadrant), BK=64, 2 K-tiles double-buffered in 128 KiB dynamic LDS.
// Per tile: 4 phases = 4 C-quadrants; each phase: ds-read frag subtile
// (12/4/8/0 b128 reads) + stage ONE half-tile (2 gld_lds x16B per thread)
// -> barrier -> 16 MFMA (setprio) -> barrier. Counted vmcnt(6) at tile
// boundaries only (3 half-tiles in flight across barriers); drain 0 before
// last tile. LDS granule swizzle g ^= (row&7), applied on BOTH sides:
// pre-swizzled global source (gld_lds writes linearly) + swizzled ds_read.
// Stage stream: tile T halves {A0@(T-2).P1, B0@(T-2).P2, B1@(T-2).P3,
// A1@(T-1).P0} -> each write lands in a region whose previous-contents
// ds_reads were issued >=1 phase (2 barriers) earlier.
// KSPLIT=4 keeps the FFN2 partial scheme: kh0 -> fp32+bias+resid in-place;
// kh1/2/3 -> bf16 partials (combined in ln_k<NX=3>).
template <int KSPLIT, bool RESID, bool OUT32, bool OUT16>
__global__ __launch_bounds__(512, 2)
void gemm8(const u16* __restrict__ A, const u16* __restrict__ Bt,
           const float* __restrict__ bias, int K, int N, int nCol,
           const float* __restrict__ resid, float* __restrict__ C32,
           u16* __restrict__ C16, u16* __restrict__ C16b,
           u16* __restrict__ C16c) {
  extern __shared__ u16 sm[];
  u16* Ab = sm;            // [2][256*64] bf16 = 2 x 32 KiB
  u16* Bb = sm + 32768;    // [2][256*64]
  const int tid = threadIdx.x;
  const int wave = tid >> 6, lane = tid & 63;
  const int l15 = lane & 15, quad = lane >> 4, l7 = l15 & 7;
  const int wm = wave >> 2, wn = wave & 3;

  int lin = blockIdx.x;
  int kh = 0;
  const int nblk = 32 * nCol;
  if constexpr (KSPLIT > 1) { kh = lin / nblk; lin -= kh * nblk; }
  const int xcd = lin & 7, local = lin >> 3;   // grids are %8==0 (192/256)
  const int row0 = (xcd * 4 + local / nCol) * 256;
  const int col0 = (local % nCol) * 256;
  const int klen = K / KSPLIT, kstart = kh * klen, nT = klen >> 6;

  // staging: thread covers rows rr and rr+64 of each 128-row half, granule
  // gg; source granule pre-swizzled so linear LDS dest + swizzled read match
  const int rr = tid >> 3;
  const int swz = ((tid & 7) ^ (rr & 7)) * 8;
  const u16* aB = A + (size_t)(row0 + rr) * K + kstart + swz;
  const u16* bB = Bt + (size_t)(col0 + rr) * K + kstart + swz;
  const int dOff = tid * 8;  // elems; = wave-uniform base + lane*16B

  auto stA = [&](int h, int T, int b) {
    const u16* s = aB + (size_t)(h * 128) * K + T * 64;
    u16* d = Ab + b * 16384 + h * 8192 + dOff;
    gld16(s, d);
    gld16(s + (size_t)64 * K, d + 4096);
  };
  auto stB = [&](int h, int T, int b) {
    const u16* s = bB + (size_t)(h * 128) * K + T * 64;
    u16* d = Bb + b * 16384 + h * 8192 + dOff;
    gld16(s, d);
    gld16(s + (size_t)64 * K, d + 4096);
  };
  auto rdA = [&](int i, int b, bf16x8 (&aF)[4][2]) {
#pragma unroll
    for (int mf = 0; mf < 4; mf++)
#pragma unroll
      for (int ks = 0; ks < 2; ks++)
        aF[mf][ks] = ldfrag(Ab + b * 16384 +
                            (i * 128 + wm * 64 + mf * 16 + l15) * 64 +
                            (((ks * 4 + quad) ^ l7) * 8));
  };
  auto rdB = [&](int j, int b, bf16x8 (&bF)[2][2]) {
#pragma unroll
    for (int nf = 0; nf < 2; nf++)
#pragma unroll
      for (int ks = 0; ks < 2; ks++)
        bF[nf][ks] = ldfrag(Bb + b * 16384 +
                            (j * 128 + wn * 32 + nf * 16 + l15) * 64 +
                            (((ks * 4 + quad) ^ l7) * 8));
  };

  f32x4 a00[4][2], a01[4][2], a10[4][2], a11[4][2];
#pragma unroll
  for (int mf = 0; mf < 4; mf++)
#pragma unroll
    for (int nf = 0; nf < 2; nf++) {
      a00[mf][nf] = (f32x4){0.f, 0.f, 0.f, 0.f};
      a01[mf][nf] = (f32x4){0.f, 0.f, 0.f, 0.f};
      a10[mf][nf] = (f32x4){0.f, 0.f, 0.f, 0.f};
      a11[mf][nf] = (f32x4){0.f, 0.f, 0.f, 0.f};
    }

  // prologue: T0 {A0,B0,B1,A1}, T1 {A0,B0,B1}; vmcnt(6) -> T0 landed,
  // T1's 3 halves stay in flight
  stA(0, 0, 0); stB(0, 0, 0); stB(1, 0, 0); stA(1, 0, 0);
  stA(0, 1, 1); stB(0, 1, 1); stB(1, 1, 1);
  vm_bar<6>();

  bf16x8 aF[4][2], bF0[2][2], bF1[2][2];
  for (int t = 0; t < nT; ++t) {
    const int b = t & 1;
    // P0 — quadrant (0,0): read A-half0 + B-half0; stage next tile's A1
    rdA(0, b, aF); rdB(0, b, bF0);
    if (t + 1 < nT) stA(1, t + 1, b ^ 1);
    bar();
    mm16(aF, bF0, a00);
    bar();
    // P1 — quadrant (0,1): read B-half1 (A regs reused); stage T+2 A0
    rdB(1, b, bF1);
    if (t + 2 < nT) stA(0, t + 2, b);
    bar();
    mm16(aF, bF1, a01);
    bar();
    // P2 — quadrant (1,0): read A-half1 (B0 regs reused); stage T+2 B0
    rdA(1, b, aF);
    if (t + 2 < nT) stB(0, t + 2, b);
    bar();
    mm16(aF, bF0, a10);
    bar();
    // P3 — quadrant (1,1): no reads; stage T+2 B1; tile-boundary vmcnt
    if (t + 2 < nT) stB(1, t + 2, b);
    bar();
    mm16(aF, bF1, a11);
    if (t + 2 < nT) vm_bar<6>();
    else if (t + 1 < nT) vm_bar<0>();
    else bar();
  }

  auto wrQ = [&](int i, int j, f32x4 (&ac)[4][2]) {
#pragma unroll
    for (int mf = 0; mf < 4; mf++)
#pragma unroll
      for (int nf = 0; nf < 2; nf++) {
        const int n = col0 + j * 128 + wn * 32 + nf * 16 + l15;
        const float bv = (kh == 0) ? bias[n] : 0.f;
#pragma unroll
        for (int r = 0; r < 4; r++) {
          const int m = row0 + i * 128 + wm * 64 + mf * 16 + quad * 4 + r;
          const size_t idx = (size_t)m * N + n;
          float val = ac[mf][nf][r] + bv;
          if constexpr (KSPLIT == 4) {
            if (kh == 0)      C32[idx] = val + resid[idx];
            else if (kh == 1) C16[idx] = f2bf(val);
            else if (kh == 2) C16b[idx] = f2bf(val);
            else              C16c[idx] = f2bf(val);
          } else {
            if constexpr (RESID) val += resid[idx];
            if constexpr (OUT32) C32[idx] = val;
            if constexpr (OUT16) C16[idx] = f2bf(val);
          }
        }
      }
  };
  wrQ(0, 0, a00); wrQ(0, 1, a01); wrQ(1, 0, a10); wrQ(1, 1, a11);
}

// ---------------- transpose V head-wise: vt[b,h,d,s] ----------------------
__global__ __launch_bounds__(256)
void vtrans(const u16* __restrict__ qkv, u16* __restrict__ vt) {
  __shared__ u16 t[64][65];
  int s0 = blockIdx.x * 64, h = blockIdx.y, b = blockIdx.z;
  int x = threadIdx.x, y = threadIdx.y;  // (64,4)
  const u16* src = qkv + (size_t)(b * 2048 + s0) * 1536 + 1024 + h * 64;
#pragma unroll
  for (int r = 0; r < 16; r++) { int s = y + 4*r; t[s][x] = src[(size_t)s * 1536 + x]; }
  __syncthreads();
  u16* dst = vt + (size_t)((b * 8 + h) * 64) * 2048 + s0;
#pragma unroll
  for (int r = 0; r < 16; r++) { int d = y + 4*r; dst[(size_t)d * 2048 + x] = t[x][d]; }
}

// ---------------- attention: block = (b, h, 128 q-rows) -------------------
#define PSTR 136
__global__ __launch_bounds__(256)
void attn_k(const u16* __restrict__ qkv, const u16* __restrict__ vt,
            const float* __restrict__ hres, float* __restrict__ attn) {
  __shared__ __align__(16) u16 smem[8192 + 8192 + 128 * PSTR];
  u16* Ks = smem;
  u16* Vts = smem + 8192;
  u16* Ps = smem + 16384;
  u16* Qs = Ps;

  const int lin = blockIdx.x;
  const int xcd = lin & 7, g = lin >> 3;
  const int c = g & 15;                 // 128-row q chunk
  const int bh = xcd * 4 + (g >> 4);    // (b,h) pinned to xcd
  const int hh = bh & 7, b = bh >> 3;
  const int s0 = c * 128;
  const int tid = threadIdx.x, wave = tid >> 6, lane = tid & 63;
  const int l15 = lane & 15, quad = lane >> 4;
  const int t_lo = (c > 4) ? c - 4 : 0;
  const int t_hi = (c + 2 < 16) ? c + 2 : 16;
  const int l7sw = l15 & 7;

  // stage Q (128x64), swizzled
  {
    const int cg = ((lane & 7) ^ (lane >> 3)) * 8;
    const int cp = (lane & 7) * 8;
#pragma unroll
    for (int q2 = 0; q2 < 4; q2++) {
      int r = wave * 32 + q2 * 8 + (lane >> 3);
      gld16(qkv + (size_t)(b * 2048 + s0 + r) * 1536 + hh * 64 + cg, Qs + r * 64 + cp);
    }
  }
  __syncthreads();
  bf16x8 qf[2][2];
#pragma unroll
  for (int qg = 0; qg < 2; qg++)
#pragma unroll
    for (int f = 0; f < 2; f++)
      qf[qg][f] = ldfrag(Qs + (qg * 64 + wave * 16 + l15) * 64 + (((f * 4 + quad) ^ l7sw) * 8));

  const u16x8 ones16 = {0x3F80, 0x3F80, 0x3F80, 0x3F80, 0x3F80, 0x3F80, 0x3F80, 0x3F80};
  const bf16x8 onesf = __builtin_bit_cast(bf16x8, ones16);

  f32x4 accO[2][4];
#pragma unroll
  for (int qg = 0; qg < 2; qg++)
#pragma unroll
    for (int i = 0; i < 4; i++) accO[qg][i] = (f32x4){0.f, 0.f, 0.f, 0.f};
  f32x4 accD[2] = {(f32x4){0.f, 0.f, 0.f, 0.f}, (f32x4){0.f, 0.f, 0.f, 0.f}};

  for (int kt = t_lo; kt < t_hi; ++kt) {
    __syncthreads();  // prior-iter reads done before restage
    {
      const int cgk = ((lane & 7) ^ (lane >> 3)) * 8;
      const int cpk = (lane & 7) * 8;
#pragma unroll
      for (int q2 = 0; q2 < 4; q2++) {  // K tile 128 rows
        int r = wave * 32 + q2 * 8 + (lane >> 3);
        gld16(qkv + (size_t)(b * 2048 + kt * 128 + r) * 1536 + 512 + hh * 64 + cgk,
              Ks + r * 64 + cpk);
      }
      const int cpv = (lane & 15) * 8;
#pragma unroll
      for (int q2 = 0; q2 < 4; q2++) {  // Vt tile 64 rows
        int d = (wave * 4 + q2) * 4 + (lane >> 4);
        int cgv = ((lane & 8) | ((lane & 7) ^ (lane >> 4) ^ ((q2 & 1) << 2))) * 8;
        gld16(vt + (size_t)((b * 8 + hh) * 64 + d) * 2048 + kt * 128 + cgv,
              Vts + d * 128 + cpv);
      }
    }
    __syncthreads();

#pragma unroll
    for (int nt = 0; nt < 8; nt++) {
      bf16x8 kf0 = ldfrag(Ks + (nt * 16 + l15) * 64 + ((quad ^ l7sw) * 8));
      bf16x8 kf1 = ldfrag(Ks + (nt * 16 + l15) * 64 + (((4 + quad) ^ l7sw) * 8));
#pragma unroll
      for (int qg = 0; qg < 2; qg++) {
        f32x4 s4 = (f32x4){0.f, 0.f, 0.f, 0.f};
        s4 = __builtin_amdgcn_mfma_f32_16x16x32_bf16(qf[qg][0], kf0, s4, 0, 0, 0);
        s4 = __builtin_amdgcn_mfma_f32_16x16x32_bf16(qf[qg][1], kf1, s4, 0, 0, 0);
#pragma unroll
        for (int r = 0; r < 4; r++) {
          float pp = exp2f(s4[r] * (1.4426950408889634f * 0.125f));  // exp(s/8)
          Ps[(qg * 64 + wave * 16 + quad * 4 + r) * PSTR + nt * 16 + l15] =
              (u16)(__builtin_bit_cast(uint32_t, pp) >> 16);  // truncate
        }
      }
    }
    // PV — wave reads only its own P rows, no cross-wave barrier needed
#pragma unroll
    for (int ki = 0; ki < 4; ki++) {
      bf16x8 pf[2];
#pragma unroll
      for (int qg = 0; qg < 2; qg++) {
        pf[qg] = ldfrag(Ps + (qg * 64 + wave * 16 + l15) * PSTR + (ki * 4 + quad) * 8);
        accD[qg] = __builtin_amdgcn_mfma_f32_16x16x32_bf16(pf[qg], onesf, accD[qg], 0, 0, 0);
      }
#pragma unroll
      for (int dt = 0; dt < 4; dt++) {
        int gg = ki * 4 + quad;
        bf16x8 vf = ldfrag(Vts + (dt * 16 + l15) * 128 + (((gg & 8) | ((gg & 7) ^ l7sw)) * 8));
#pragma unroll
        for (int qg = 0; qg < 2; qg++)
          accO[qg][dt] = __builtin_amdgcn_mfma_f32_16x16x32_bf16(pf[qg], vf, accO[qg][dt], 0, 0, 0);
      }
    }
  }
#pragma unroll
  for (int qg = 0; qg < 2; qg++)
#pragma unroll
    for (int r = 0; r < 4; r++) {
      float dinv = 1.0f / accD[qg][r];
      int m = s0 + qg * 64 + wave * 16 + quad * 4 + r;
#pragma unroll
      for (int dt = 0; dt < 4; dt++) {
        size_t idx = (size_t)(b * 2048 + m) * 512 + hh * 64 + dt * 16 + l15;
        attn[idx] = accO[qg][dt][r] * dinv + hres[idx];
      }
    }
}

extern "C" void kernel_launch(void* const* d_in, const int* in_sizes, int n_in,
                              void* d_out, int out_size, void* d_ws, size_t ws_size,
                              hipStream_t stream) {
  (void)in_sizes; (void)n_in; (void)out_size; (void)ws_size;
  const float* x       = (const float*)d_in[0];
  const float* ln_in_g = (const float*)d_in[2];
  const float* ln_in_b = (const float*)d_in[3];
  const float* wq = (const float*)d_in[4];
  const float* bq = (const float*)d_in[5];
  const float* wk = (const float*)d_in[6];
  const float* bk = (const float*)d_in[7];
  const float* wv = (const float*)d_in[8];
  const float* bv = (const float*)d_in[9];
  const float* ln1_g = (const float*)d_in[10];
  const float* ln1_b = (const float*)d_in[11];
  const float* w1 = (const float*)d_in[12];
  const float* b1 = (const float*)d_in[13];
  const float* w2 = (const float*)d_in[14];
  const float* b2 = (const float*)d_in[15];
  const float* ln2_g = (const float*)d_in[16];
  const float* ln2_b = (const float*)d_in[17];

  char* ws = (char*)d_ws;
  size_t off = 0;
  auto alloc = [&](size_t bytes) {
    void* p = ws + off;
    off = (off + bytes + 255) & ~(size_t)255;
    return p;
  };
  u16*   wqkvt = (u16*)  alloc((size_t)1536 * 512 * 2);
  float* bqkv  = (float*)alloc(1536 * 4);
  u16*   w1t   = (u16*)  alloc((size_t)2048 * 512 * 2);
  u16*   w2t   = (u16*)  alloc((size_t)512 * 2048 * 2);
  float* h32   = (float*)alloc((size_t)M_ * 512 * 4);   // hres; later FFN2 kh2+kh3 partials
  u16*   h16   = (u16*)  alloc((size_t)M_ * 512 * 2);   // ln-in bf16 / o16 / FFN2 kh1 partial
  u16*   qkv16 = (u16*)  alloc((size_t)M_ * 1536 * 2);  // + vtb = f16b (FFN mid)
  u16*   vtb   = (u16*)  alloc((size_t)B_ * H_ * 64 * 2048 * 2);  // part of f16b span — never reused!
  float* attn32= (float*)alloc((size_t)M_ * 512 * 4);   // attn out; FFN2 kh0 in-place
  u16*   o16   = h16;
  u16*   f16b  = qkv16;  // 8192*2048*2 bytes spans qkv16+vtb exactly
  u16*   p2b   = (u16*)h32;
  u16*   p3b   = (u16*)h32 + (size_t)M_ * 512;
  (void)vtb;

  static bool attrSet = false;
  if (!attrSet) {
    hipFuncSetAttribute(reinterpret_cast<const void*>(&gemm8<1, false, false, true>),
                        hipFuncAttributeMaxDynamicSharedMemorySize, 131072);
    hipFuncSetAttribute(reinterpret_cast<const void*>(&gemm8<4, false, false, false>),
                        hipFuncAttributeMaxDynamicSharedMemorySize, 131072);
    attrSet = true;
  }

  prep<<<dim3(2822), 256, 0, stream>>>(wq, wk, wv, w1, w2, bq, bk, bv,
                                       wqkvt, w1t, w2t, bqkv);

  ln_k<true, true, 0><<<M_, 128, 0, stream>>>(x, ln_in_g, ln_in_b, h32, h16,
                                              nullptr, nullptr, nullptr);
  // QKV: M=8192 N=1536 K=512 -> 32x6 = 192 blocks
  gemm8<1, false, false, true><<<dim3(192), 512, 131072, stream>>>(
      h16, wqkvt, bqkv, 512, 1536, 6, nullptr, nullptr, qkv16, nullptr, nullptr);
  vtrans<<<dim3(32, 8, 4), dim3(64, 4), 0, stream>>>(qkv16, vtb);
  attn_k<<<dim3(512), 256, 0, stream>>>(qkv16, vtb, h32, attn32);
  ln_k<false, true, 0><<<M_, 128, 0, stream>>>(attn32, ln1_g, ln1_b, nullptr, o16,
                                               nullptr, nullptr, nullptr);
  // FFN1: M=8192 N=2048 K=512 -> 32x8 = 256 blocks
  gemm8<1, false, false, true><<<dim3(256), 512, 131072, stream>>>(
      o16, w1t, b1, 512, 2048, 8, nullptr, nullptr, f16b, nullptr, nullptr);
  // FFN2: M=8192 N=512 K=2048, KSPLIT=4 -> 32x2x4 = 256 blocks
  gemm8<4, false, false, false><<<dim3(256), 512, 131072, stream>>>(
      f16b, w2t, b2, 2048, 512, 2, attn32, attn32, h16, p2b, p3b);
  ln_k<true, false, 3><<<M_, 128, 0, stream>>>(attn32, ln2_g, ln2_b, (float*)d_out,
                                               nullptr, h16, p2b, p3b);
}

// Round 2
// 306.213 us; speedup vs baseline: 1.0029x; 1.0029x over previous
//
#include <hip/hip_runtime.h>
#include <stdint.h>

#define B_ 4
#define S_ 2048
#define D_ 512
#define H_ 8
#define FFN_ 2048
#define M_ (B_*S_)

typedef unsigned short u16;
typedef __attribute__((ext_vector_type(8))) __bf16 bf16x8;
typedef __attribute__((ext_vector_type(8))) u16 u16x8;
typedef __attribute__((ext_vector_type(4))) u16 u16x4;
typedef __attribute__((ext_vector_type(4))) float f32x4;

__device__ __forceinline__ u16 f2bf(float f) {
  uint32_t u = __builtin_bit_cast(uint32_t, f);
  u += 0x7FFFu + ((u >> 16) & 1u);
  return (u16)(u >> 16);
}
__device__ __forceinline__ bf16x8 ldfrag(const u16* p) {
  return __builtin_bit_cast(bf16x8, *(const u16x8*)p);
}
__device__ __forceinline__ void gld16(const void* g, void* l) {
  __builtin_amdgcn_global_load_lds(
      (const __attribute__((address_space(1))) void*)g,
      (__attribute__((address_space(3))) void*)l, 16, 0, 0);
}
// raw barrier with partial vmcnt wait (GEMM K-loop only): keeps prefetch
// loads in flight across the barrier. Safe: ds_reads are consumed before
// any wave reaches the barrier (compiler lgkmcnt waits precede the MFMAs).
template <int N>
__device__ __forceinline__ void wait_vm_barrier() {
  if constexpr (N == 0)       asm volatile("s_waitcnt vmcnt(0)\n\ts_barrier" ::: "memory");
  else if constexpr (N == 4)  asm volatile("s_waitcnt vmcnt(4)\n\ts_barrier" ::: "memory");
  else if constexpr (N == 8)  asm volatile("s_waitcnt vmcnt(8)\n\ts_barrier" ::: "memory");
  else if constexpr (N == 12) asm volatile("s_waitcnt vmcnt(12)\n\ts_barrier" ::: "memory");
}

// ---------------- merged weight prep: all transposes + bias concat --------
__global__ __launch_bounds__(256)
void prep(const float* __restrict__ wq, const float* __restrict__ wk,
          const float* __restrict__ wv, const float* __restrict__ w1,
          const float* __restrict__ w2, const float* __restrict__ bq,
          const float* __restrict__ bk, const float* __restrict__ bv,
          u16* __restrict__ wqkvt, u16* __restrict__ w1t,
          u16* __restrict__ w2t, float* __restrict__ bqkv) {
  int id = blockIdx.x, tid = threadIdx.x;
  if (id >= 2816) {
    int i = (id - 2816) * 256 + tid;
    bqkv[i] = i < 512 ? bq[i] : (i < 1024 ? bk[i - 512] : bv[i - 1024]);
    return;
  }
  __shared__ float t[32][33];
  const float* W; u16* dst; int K, N, bx, by;
  if (id < 768) {
    int z = id >> 8, r = id & 255;
    W = z == 0 ? wq : (z == 1 ? wk : wv);
    dst = wqkvt + (size_t)z * 512 * 512; K = 512; N = 512;
    bx = r & 15; by = r >> 4;
  } else if (id < 1792) {
    int r = id - 768; W = w1; dst = w1t; K = 512; N = 2048;
    bx = r & 63; by = r >> 6;
  } else {
    int r = id - 1792; W = w2; dst = w2t; K = 2048; N = 512;
    bx = r & 15; by = r >> 4;
  }
  int n0 = bx * 32, k0 = by * 32, x = tid & 31, y = tid >> 5;
#pragma unroll
  for (int r = 0; r < 4; r++) t[y + 8*r][x] = W[(size_t)(k0 + y + 8*r) * N + n0 + x];
  __syncthreads();
#pragma unroll
  for (int r = 0; r < 4; r++) dst[(size_t)(n0 + y + 8*r) * K + k0 + x] = f2bf(t[x][y + 8*r]);
}

// ---------------- layernorm over rows of 512 ------------------------------
// NX = number of bf16 partial arrays to add to x (split-K combine fused)
template <bool OUT32, bool OUT16, int NX>
__global__ __launch_bounds__(128)
void ln_k(const float* __restrict__ x, const float* __restrict__ g,
          const float* __restrict__ bta, float* __restrict__ y32,
          u16* __restrict__ y16, const u16* __restrict__ p1,
          const u16* __restrict__ p2, const u16* __restrict__ p3) {
  int row = blockIdx.x;
  int t = threadIdx.x;
  const float* xr = x + (size_t)row * 512;
  f32x4 v = *(const f32x4*)(xr + t * 4);
  if constexpr (NX >= 1) {
    u16x4 a = *(const u16x4*)(p1 + (size_t)row * 512 + t * 4);
#pragma unroll
    for (int j = 0; j < 4; j++) v[j] += __builtin_bit_cast(float, (uint32_t)a[j] << 16);
  }
  if constexpr (NX >= 2) {
    u16x4 a = *(const u16x4*)(p2 + (size_t)row * 512 + t * 4);
#pragma unroll
    for (int j = 0; j < 4; j++) v[j] += __builtin_bit_cast(float, (uint32_t)a[j] << 16);
  }
  if constexpr (NX >= 3) {
    u16x4 a = *(const u16x4*)(p3 + (size_t)row * 512 + t * 4);
#pragma unroll
    for (int j = 0; j < 4; j++) v[j] += __builtin_bit_cast(float, (uint32_t)a[j] << 16);
  }
  float s = v.x + v.y + v.z + v.w;
  float s2 = v.x*v.x + v.y*v.y + v.z*v.z + v.w*v.w;
#pragma unroll
  for (int m = 32; m; m >>= 1) { s += __shfl_xor(s, m); s2 += __shfl_xor(s2, m); }
  __shared__ float p[4];
  int wv = t >> 6;
  if ((t & 63) == 0) { p[wv] = s; p[2 + wv] = s2; }
  __syncthreads();
  s = p[0] + p[1]; s2 = p[2] + p[3];
  float mean = s * (1.f / 512.f);
  float var = s2 * (1.f / 512.f) - mean * mean;
  float rs = rsqrtf(var + 1e-5f);
#pragma unroll
  for (int j = 0; j < 4; j++) {
    float o = (v[j] - mean) * rs * g[t*4 + j] + bta[t*4 + j];
    if constexpr (OUT32) y32[(size_t)row * 512 + t*4 + j] = o;
    if constexpr (OUT16) y16[(size_t)row * 512 + t*4 + j] = f2bf(o);
  }
}

// ---------------- GEMM: C[M,N] = A[M,K](bf16) @ Wt[N,K]^T + bias ----------
// 5-buffer LDS pipeline (depth-4 prefetch slack ~= 4 iters > effective HBM
// latency), ONE raw barrier per K-iter with counted vmcnt (graded drain at
// the tail: 12/8/4/0 for L=4 loads/iter). 256 thr / 4 waves, 128x(NTW*32)
// tile, BK=32. LDS 5*(8+NTW*2) KiB -> 80 KiB at NTW=4 -> 2 blocks/CU, so
// block-level TLP is retained on top of the deeper prefetch.
// KSPLIT=4: kh0 -> fp32 + bias + resid (in-place safe: one thread per elem);
// kh1/2/3 -> bf16 partials to C16/C16b/C16c (combined in ln_k<NX=3>).
// Partial buffers MUST NOT alias the A operand (r10 bug: kh2->vtb raced
// with A reads, f16b spans qkv16+vtb).
// LDS swizzle: granule c of row r stored at c ^ ((r>>1)&3).
// 1-D grid, XCD-aware raster keeps each A row-stripe in one XCD's L2.
template <int NTW, int NCOL, int KSPLIT, bool RESID, bool OUT32, bool OUT16>
__global__ __launch_bounds__(256)
void gemm_db(const u16* __restrict__ A, const u16* __restrict__ Bt,
             const float* __restrict__ bias, int K, int N,
             const float* resid, float* C32, u16* __restrict__ C16,
             u16* __restrict__ C16b, u16* __restrict__ C16c) {
  __shared__ __align__(16) u16 As[5][128 * 32];
  __shared__ __align__(16) u16 Bs[5][NTW * 1024];
  const int tid = threadIdx.x;
  const int wave = tid >> 6, lane = tid & 63;
  const int l15 = lane & 15, quad = lane >> 4;
  const int wm = wave >> 1, wn = wave & 1;

  int lin = blockIdx.x;
  int kh = 0;
  if constexpr (KSPLIT > 1) {
    const int nblk = (M_ / 128) * NCOL;
    kh = lin / nblk;
    lin -= kh * nblk;
  }
  const int rpx = (M_ / 128) / 8;              // row tiles per XCD
  const int xcd = lin & 7, local = lin >> 3;
  const int row0 = (xcd * rpx + local / NCOL) * 128;
  const int col0 = (local % NCOL) * (NTW * 32);
  const int klen = K / KSPLIT;
  const int kstart = kh * klen;

  f32x4 acc[4][NTW];
#pragma unroll
  for (int i = 0; i < 4; i++)
#pragma unroll
    for (int j = 0; j < NTW; j++) acc[i][j] = (f32x4){0.f, 0.f, 0.f, 0.f};

  const int lr = lane >> 2;
  const int lc = ((lane & 3) ^ ((lane >> 3) & 3)) * 8;  // swizzled source granule
  const u16* aG0 = A + (size_t)(row0 + (wave * 2) * 16 + lr) * K + lc;
  const u16* aG1 = A + (size_t)(row0 + (wave * 2 + 1) * 16 + lr) * K + lc;
  const int aO0 = (wave * 2) * 512 + lane * 8;
  const int aO1 = (wave * 2 + 1) * 512 + lane * 8;
  const u16* bG[NTW / 2];
  int bO[NTW / 2];
#pragma unroll
  for (int i = 0; i < NTW / 2; i++) {
    int ch = wave * (NTW / 2) + i;
    bG[i] = Bt + (size_t)(col0 + ch * 16 + lr) * K + lc;
    bO[i] = ch * 512 + lane * 8;
  }
  const int rsw = (l15 >> 1) & 3;  // frag-read swizzle term

  auto issue = [&](int kof, int buf) {
    gld16(aG0 + kof, &As[buf][aO0]);
    gld16(aG1 + kof, &As[buf][aO1]);
#pragma unroll
    for (int i = 0; i < NTW / 2; i++) gld16(bG[i] + kof, &Bs[buf][bO[i]]);
  };

  const int nIter = klen >> 5;   // = 16 for all instantiations here
  issue(kstart, 0);
  issue(kstart + 32, 1);
  issue(kstart + 64, 2);
  issue(kstart + 96, 3);

  int cur = 0;
  for (int it = 0; it < nIter; it++) {
    // graded counted drains: steady state has 4 tiles (16 loads) in flight;
    // wait leaves newest 3 tiles (12) in flight -> tile `it` has landed.
    if (it + 3 < nIter)      wait_vm_barrier<12>();
    else if (it + 2 < nIter) wait_vm_barrier<8>();
    else if (it + 1 < nIter) wait_vm_barrier<4>();
    else                     wait_vm_barrier<0>();
    int pf = cur == 0 ? 4 : cur - 1;            // (cur+4) mod 5
    if (it + 4 < nIter) issue(kstart + ((it + 4) << 5), pf);
    bf16x8 af[4], bf[NTW];
#pragma unroll
    for (int mt = 0; mt < 4; mt++)
      af[mt] = ldfrag(&As[cur][(wm * 64 + mt * 16 + l15) * 32 + ((quad ^ rsw) * 8)]);
#pragma unroll
    for (int nt = 0; nt < NTW; nt++)
      bf[nt] = ldfrag(&Bs[cur][(wn * (NTW * 16) + nt * 16 + l15) * 32 + ((quad ^ rsw) * 8)]);
#pragma unroll
    for (int mt = 0; mt < 4; mt++)
#pragma unroll
      for (int nt = 0; nt < NTW; nt++)
        acc[mt][nt] = __builtin_amdgcn_mfma_f32_16x16x32_bf16(af[mt], bf[nt], acc[mt][nt], 0, 0, 0);
    cur = cur == 4 ? 0 : cur + 1;
  }
#pragma unroll
  for (int mt = 0; mt < 4; mt++)
#pragma unroll
    for (int nt = 0; nt < NTW; nt++) {
      int n = col0 + wn * (NTW * 16) + nt * 16 + l15;
      float bv = (kh == 0) ? bias[n] : 0.f;
#pragma unroll
      for (int r = 0; r < 4; r++) {
        int m = row0 + wm * 64 + mt * 16 + quad * 4 + r;
        size_t idx = (size_t)m * N + n;
        float val = acc[mt][nt][r] + bv;
        if constexpr (KSPLIT == 4) {
          if (kh == 0)      C32[idx] = val + resid[idx];
          else if (kh == 1) C16[idx] = f2bf(val);
          else if (kh == 2) C16b[idx] = f2bf(val);
          else              C16c[idx] = f2bf(val);
        } else {
          if constexpr (RESID) val += resid[idx];
          if constexpr (OUT32) C32[idx] = val;
          if constexpr (OUT16) C16[idx] = f2bf(val);
        }
      }
    }
}

// ---------------- transpose V head-wise: vt[b,h,d,s] ----------------------
__global__ __launch_bounds__(256)
void vtrans(const u16* __restrict__ qkv, u16* __restrict__ vt) {
  __shared__ u16 t[64][65];
  int s0 = blockIdx.x * 64, h = blockIdx.y, b = blockIdx.z;
  int x = threadIdx.x, y = threadIdx.y;  // (64,4)
  const u16* src = qkv + (size_t)(b * 2048 + s0) * 1536 + 1024 + h * 64;
#pragma unroll
  for (int r = 0; r < 16; r++) { int s = y + 4*r; t[s][x] = src[(size_t)s * 1536 + x]; }
  __syncthreads();
  u16* dst = vt + (size_t)((b * 8 + h) * 64) * 2048 + s0;
#pragma unroll
  for (int r = 0; r < 16; r++) { int d = y + 4*r; dst[(size_t)d * 2048 + x] = t[x][d]; }
}

// ---------------- attention: block = (b, h, 128 q-rows) -------------------
#define PSTR 136
__global__ __launch_bounds__(256)
void attn_k(const u16* __restrict__ qkv, const u16* __restrict__ vt,
            const float* __restrict__ hres, float* __restrict__ attn) {
  __shared__ __align__(16) u16 smem[8192 + 8192 + 128 * PSTR];
  u16* Ks = smem;
  u16* Vts = smem + 8192;
  u16* Ps = smem + 16384;
  u16* Qs = Ps;

  const int lin = blockIdx.x;
  const int xcd = lin & 7, g = lin >> 3;
  const int c = g & 15;                 // 128-row q chunk
  const int bh = xcd * 4 + (g >> 4);    // (b,h) pinned to xcd
  const int hh = bh & 7, b = bh >> 3;
  const int s0 = c * 128;
  const int tid = threadIdx.x, wave = tid >> 6, lane = tid & 63;
  const int l15 = lane & 15, quad = lane >> 4;
  const int t_lo = (c > 4) ? c - 4 : 0;
  const int t_hi = (c + 2 < 16) ? c + 2 : 16;
  const int l7sw = l15 & 7;

  // stage Q (128x64), swizzled
  {
    const int cg = ((lane & 7) ^ (lane >> 3)) * 8;
    const int cp = (lane & 7) * 8;
#pragma unroll
    for (int q2 = 0; q2 < 4; q2++) {
      int r = wave * 32 + q2 * 8 + (lane >> 3);
      gld16(qkv + (size_t)(b * 2048 + s0 + r) * 1536 + hh * 64 + cg, Qs + r * 64 + cp);
    }
  }
  __syncthreads();
  bf16x8 qf[2][2];
#pragma unroll
  for (int qg = 0; qg < 2; qg++)
#pragma unroll
    for (int f = 0; f < 2; f++)
      qf[qg][f] = ldfrag(Qs + (qg * 64 + wave * 16 + l15) * 64 + (((f * 4 + quad) ^ l7sw) * 8));

  const u16x8 ones16 = {0x3F80, 0x3F80, 0x3F80, 0x3F80, 0x3F80, 0x3F80, 0x3F80, 0x3F80};
  const bf16x8 onesf = __builtin_bit_cast(bf16x8, ones16);

  f32x4 accO[2][4];
#pragma unroll
  for (int qg = 0; qg < 2; qg++)
#pragma unroll
    for (int i = 0; i < 4; i++) accO[qg][i] = (f32x4){0.f, 0.f, 0.f, 0.f};
  f32x4 accD[2] = {(f32x4){0.f, 0.f, 0.f, 0.f}, (f32x4){0.f, 0.f, 0.f, 0.f}};

  for (int kt = t_lo; kt < t_hi; ++kt) {
    __syncthreads();  // prior-iter reads done before restage
    {
      const int cgk = ((lane & 7) ^ (lane >> 3)) * 8;
      const int cpk = (lane & 7) * 8;
#pragma unroll
      for (int q2 = 0; q2 < 4; q2++) {  // K tile 128 rows
        int r = wave * 32 + q2 * 8 + (lane >> 3);
        gld16(qkv + (size_t)(b * 2048 + kt * 128 + r) * 1536 + 512 + hh * 64 + cgk,
              Ks + r * 64 + cpk);
      }
      const int cpv = (lane & 15) * 8;
#pragma unroll
      for (int q2 = 0; q2 < 4; q2++) {  // Vt tile 64 rows
        int d = (wave * 4 + q2) * 4 + (lane >> 4);
        int cgv = ((lane & 8) | ((lane & 7) ^ (lane >> 4) ^ ((q2 & 1) << 2))) * 8;
        gld16(vt + (size_t)((b * 8 + hh) * 64 + d) * 2048 + kt * 128 + cgv,
              Vts + d * 128 + cpv);
      }
    }
    __syncthreads();

#pragma unroll
    for (int nt = 0; nt < 8; nt++) {
      bf16x8 kf0 = ldfrag(Ks + (nt * 16 + l15) * 64 + ((quad ^ l7sw) * 8));
      bf16x8 kf1 = ldfrag(Ks + (nt * 16 + l15) * 64 + (((4 + quad) ^ l7sw) * 8));
#pragma unroll
      for (int qg = 0; qg < 2; qg++) {
        f32x4 s4 = (f32x4){0.f, 0.f, 0.f, 0.f};
        s4 = __builtin_amdgcn_mfma_f32_16x16x32_bf16(qf[qg][0], kf0, s4, 0, 0, 0);
        s4 = __builtin_amdgcn_mfma_f32_16x16x32_bf16(qf[qg][1], kf1, s4, 0, 0, 0);
#pragma unroll
        for (int r = 0; r < 4; r++) {
          float pp = exp2f(s4[r] * (1.4426950408889634f * 0.125f));  // exp(s/8)
          Ps[(qg * 64 + wave * 16 + quad * 4 + r) * PSTR + nt * 16 + l15] =
              (u16)(__builtin_bit_cast(uint32_t, pp) >> 16);  // truncate
        }
      }
    }
    // PV — wave reads only its own P rows, no cross-wave barrier needed
#pragma unroll
    for (int ki = 0; ki < 4; ki++) {
      bf16x8 pf[2];
#pragma unroll
      for (int qg = 0; qg < 2; qg++) {
        pf[qg] = ldfrag(Ps + (qg * 64 + wave * 16 + l15) * PSTR + (ki * 4 + quad) * 8);
        accD[qg] = __builtin_amdgcn_mfma_f32_16x16x32_bf16(pf[qg], onesf, accD[qg], 0, 0, 0);
      }
#pragma unroll
      for (int dt = 0; dt < 4; dt++) {
        int gg = ki * 4 + quad;
        bf16x8 vf = ldfrag(Vts + (dt * 16 + l15) * 128 + (((gg & 8) | ((gg & 7) ^ l7sw)) * 8));
#pragma unroll
        for (int qg = 0; qg < 2; qg++)
          accO[qg][dt] = __builtin_amdgcn_mfma_f32_16x16x32_bf16(pf[qg], vf, accO[qg][dt], 0, 0, 0);
      }
    }
  }
#pragma unroll
  for (int qg = 0; qg < 2; qg++)
#pragma unroll
    for (int r = 0; r < 4; r++) {
      float dinv = 1.0f / accD[qg][r];
      int m = s0 + qg * 64 + wave * 16 + quad * 4 + r;
#pragma unroll
      for (int dt = 0; dt < 4; dt++) {
        size_t idx = (size_t)(b * 2048 + m) * 512 + hh * 64 + dt * 16 + l15;
        attn[idx] = accO[qg][dt][r] * dinv + hres[idx];
      }
    }
}

extern "C" void kernel_launch(void* const* d_in, const int* in_sizes, int n_in,
                              void* d_out, int out_size, void* d_ws, size_t ws_size,
                              hipStream_t stream) {
  (void)in_sizes; (void)n_in; (void)out_size; (void)ws_size;
  const float* x       = (const float*)d_in[0];
  const float* ln_in_g = (const float*)d_in[2];
  const float* ln_in_b = (const float*)d_in[3];
  const float* wq = (const float*)d_in[4];
  const float* bq = (const float*)d_in[5];
  const float* wk = (const float*)d_in[6];
  const float* bk = (const float*)d_in[7];
  const float* wv = (const float*)d_in[8];
  const float* bv = (const float*)d_in[9];
  const float* ln1_g = (const float*)d_in[10];
  const float* ln1_b = (const float*)d_in[11];
  const float* w1 = (const float*)d_in[12];
  const float* b1 = (const float*)d_in[13];
  const float* w2 = (const float*)d_in[14];
  const float* b2 = (const float*)d_in[15];
  const float* ln2_g = (const float*)d_in[16];
  const float* ln2_b = (const float*)d_in[17];

  char* ws = (char*)d_ws;
  size_t off = 0;
  auto alloc = [&](size_t bytes) {
    void* p = ws + off;
    off = (off + bytes + 255) & ~(size_t)255;
    return p;
  };
  u16*   wqkvt = (u16*)  alloc((size_t)1536 * 512 * 2);
  float* bqkv  = (float*)alloc(1536 * 4);
  u16*   w1t   = (u16*)  alloc((size_t)2048 * 512 * 2);
  u16*   w2t   = (u16*)  alloc((size_t)512 * 2048 * 2);
  float* h32   = (float*)alloc((size_t)M_ * 512 * 4);   // hres; later FFN2 kh2+kh3 partials
  u16*   h16   = (u16*)  alloc((size_t)M_ * 512 * 2);   // ln-in bf16 / o16 / FFN2 kh1 partial
  u16*   qkv16 = (u16*)  alloc((size_t)M_ * 1536 * 2);  // + vtb = f16b (FFN mid)
  u16*   vtb   = (u16*)  alloc((size_t)B_ * H_ * 64 * 2048 * 2);  // part of f16b span — never reused!
  float* attn32= (float*)alloc((size_t)M_ * 512 * 4);   // attn out; FFN2 kh0 in-place
  u16*   o16   = h16;
  u16*   f16b  = qkv16;  // 8192*2048*2 bytes spans qkv16+vtb exactly
  // FFN2 bf16 partials: kh1 -> h16 (free after FFN1); kh2/kh3 -> the two
  // halves of h32 (16 MB fp32 hres buffer, free after attn_k). None of
  // these alias f16b (the FFN2 A operand) — that aliasing was the r10 bug.
  u16*   p2b   = (u16*)h32;
  u16*   p3b   = (u16*)h32 + (size_t)M_ * 512;

  prep<<<dim3(2822), 256, 0, stream>>>(wq, wk, wv, w1, w2, bq, bk, bv,
                                       wqkvt, w1t, w2t, bqkv);

  ln_k<true, true, 0><<<M_, 128, 0, stream>>>(x, ln_in_g, ln_in_b, h32, h16,
                                              nullptr, nullptr, nullptr);
  // QKV: M=8192 N=1536 K=512, tile 128x128 -> 12*64 = 768 blocks
  gemm_db<4, 12, 1, false, false, true><<<dim3(12 * 64), 256, 0, stream>>>(
      h16, wqkvt, bqkv, 512, 1536, nullptr, nullptr, qkv16, nullptr, nullptr);
  vtrans<<<dim3(32, 8, 4), dim3(64, 4), 0, stream>>>(qkv16, vtb);
  attn_k<<<dim3(512), 256, 0, stream>>>(qkv16, vtb, h32, attn32);
  ln_k<false, true, 0><<<M_, 128, 0, stream>>>(attn32, ln1_g, ln1_b, nullptr, o16,
                                               nullptr, nullptr, nullptr);
  // FFN1: M=8192 N=2048 K=512, tile 128x128 -> 16*64 = 1024 blocks
  gemm_db<4, 16, 1, false, false, true><<<dim3(16 * 64), 256, 0, stream>>>(
      o16, w1t, b1, 512, 2048, nullptr, nullptr, f16b, nullptr, nullptr);
  // FFN2: M=8192 N=512 K=2048, tile 128x128, KSPLIT=4 -> 4*4*64 = 1024 blocks
  gemm_db<4, 4, 4, false, false, false><<<dim3(4 * 4 * 64), 256, 0, stream>>>(
      f16b, w2t, b2, 2048, 512, attn32, attn32, h16, p2b, p3b);
  ln_k<true, false, 3><<<M_, 128, 0, stream>>>(attn32, ln2_g, ln2_b, (float*)d_out,
                                               nullptr, h16, p2b, p3b);
}

// Round 3
// 295.373 us; speedup vs baseline: 1.0397x; 1.0367x over previous
//
#include <hip/hip_runtime.h>
#include <stdint.h>

#define B_ 4
#define S_ 2048
#define D_ 512
#define H_ 8
#define FFN_ 2048
#define M_ (B_*S_)

typedef unsigned short u16;
typedef __attribute__((ext_vector_type(8))) __bf16 bf16x8;
typedef __attribute__((ext_vector_type(8))) u16 u16x8;
typedef __attribute__((ext_vector_type(4))) u16 u16x4;
typedef __attribute__((ext_vector_type(4))) float f32x4;

__device__ __forceinline__ u16 f2bf(float f) {
  uint32_t u = __builtin_bit_cast(uint32_t, f);
  u += 0x7FFFu + ((u >> 16) & 1u);
  return (u16)(u >> 16);
}
__device__ __forceinline__ bf16x8 ldfrag(const u16* p) {
  return __builtin_bit_cast(bf16x8, *(const u16x8*)p);
}
__device__ __forceinline__ void gld16(const void* g, void* l) {
  __builtin_amdgcn_global_load_lds(
      (const __attribute__((address_space(1))) void*)g,
      (__attribute__((address_space(3))) void*)l, 16, 0, 0);
}

// ---------------- merged weight prep: all transposes + bias concat --------
__global__ __launch_bounds__(256)
void prep(const float* __restrict__ wq, const float* __restrict__ wk,
          const float* __restrict__ wv, const float* __restrict__ w1,
          const float* __restrict__ w2, const float* __restrict__ bq,
          const float* __restrict__ bk, const float* __restrict__ bv,
          u16* __restrict__ wqkvt, u16* __restrict__ w1t,
          u16* __restrict__ w2t, float* __restrict__ bqkv) {
  int id = blockIdx.x, tid = threadIdx.x;
  if (id >= 2816) {
    int i = (id - 2816) * 256 + tid;
    bqkv[i] = i < 512 ? bq[i] : (i < 1024 ? bk[i - 512] : bv[i - 1024]);
    return;
  }
  __shared__ float t[32][33];
  const float* W; u16* dst; int K, N, bx, by;
  if (id < 768) {
    int z = id >> 8, r = id & 255;
    W = z == 0 ? wq : (z == 1 ? wk : wv);
    dst = wqkvt + (size_t)z * 512 * 512; K = 512; N = 512;
    bx = r & 15; by = r >> 4;
  } else if (id < 1792) {
    int r = id - 768; W = w1; dst = w1t; K = 512; N = 2048;
    bx = r & 63; by = r >> 6;
  } else {
    int r = id - 1792; W = w2; dst = w2t; K = 2048; N = 512;
    bx = r & 15; by = r >> 4;
  }
  int n0 = bx * 32, k0 = by * 32, x = tid & 31, y = tid >> 5;
#pragma unroll
  for (int r = 0; r < 4; r++) t[y + 8*r][x] = W[(size_t)(k0 + y + 8*r) * N + n0 + x];
  __syncthreads();
#pragma unroll
  for (int r = 0; r < 4; r++) dst[(size_t)(n0 + y + 8*r) * K + k0 + x] = f2bf(t[x][y + 8*r]);
}

// ---------------- layernorm over rows of 512 ------------------------------
// NX = number of bf16 partial arrays to add to x (split-K combine fused)
template <bool OUT32, bool OUT16, int NX>
__global__ __launch_bounds__(128)
void ln_k(const float* __restrict__ x, const float* __restrict__ g,
          const float* __restrict__ bta, float* __restrict__ y32,
          u16* __restrict__ y16, const u16* __restrict__ p1,
          const u16* __restrict__ p2, const u16* __restrict__ p3) {
  int row = blockIdx.x;
  int t = threadIdx.x;
  const float* xr = x + (size_t)row * 512;
  f32x4 v = *(const f32x4*)(xr + t * 4);
  if constexpr (NX >= 1) {
    u16x4 a = *(const u16x4*)(p1 + (size_t)row * 512 + t * 4);
#pragma unroll
    for (int j = 0; j < 4; j++) v[j] += __builtin_bit_cast(float, (uint32_t)a[j] << 16);
  }
  if constexpr (NX >= 2) {
    u16x4 a = *(const u16x4*)(p2 + (size_t)row * 512 + t * 4);
#pragma unroll
    for (int j = 0; j < 4; j++) v[j] += __builtin_bit_cast(float, (uint32_t)a[j] << 16);
  }
  if constexpr (NX >= 3) {
    u16x4 a = *(const u16x4*)(p3 + (size_t)row * 512 + t * 4);
#pragma unroll
    for (int j = 0; j < 4; j++) v[j] += __builtin_bit_cast(float, (uint32_t)a[j] << 16);
  }
  float s = v.x + v.y + v.z + v.w;
  float s2 = v.x*v.x + v.y*v.y + v.z*v.z + v.w*v.w;
#pragma unroll
  for (int m = 32; m; m >>= 1) { s += __shfl_xor(s, m); s2 += __shfl_xor(s2, m); }
  __shared__ float p[4];
  int wv = t >> 6;
  if ((t & 63) == 0) { p[wv] = s; p[2 + wv] = s2; }
  __syncthreads();
  s = p[0] + p[1]; s2 = p[2] + p[3];
  float mean = s * (1.f / 512.f);
  float var = s2 * (1.f / 512.f) - mean * mean;
  float rs = rsqrtf(var + 1e-5f);
#pragma unroll
  for (int j = 0; j < 4; j++) {
    float o = (v[j] - mean) * rs * g[t*4 + j] + bta[t*4 + j];
    if constexpr (OUT32) y32[(size_t)row * 512 + t*4 + j] = o;
    if constexpr (OUT16) y16[(size_t)row * 512 + t*4 + j] = f2bf(o);
  }
}

// ---------------- GEMM: C[M,N] = A[M,K](bf16) @ Wt[N,K]^T + bias ----------
// TLP-first structure: 2-buffer LDS, ONE __syncthreads per K-iter
// (stage next tile -> ds_read current -> MFMA -> barrier; compiler-managed
// waitcnts, no inline asm). LDS per block: NTW=2 -> 24 KiB (6 blocks/CU,
// 24 waves), NTW=4 -> 32 KiB (5 blocks/CU, 20 waves). Rationale (r0-r2
// post-mortem): per-block iteration stall is a fixed full-drain ~2-4k cyc
// that counted-vmcnt inline asm does NOT remove (hipcc re-inserts drains);
// MfmaUtil scaled linearly with blocks/CU across r0/r1/r2, so maximize
// resident blocks and let independent barrier groups interleave stalls.
// KSPLIT=4: kh0 -> fp32 + bias + resid (in-place safe: one thread per elem);
// kh1/2/3 -> bf16 partials to C16/C16b/C16c (combined in ln_k<NX=3>).
// Partial buffers MUST NOT alias the A operand (r10 bug).
// LDS swizzle: granule c of row r stored at c ^ ((r>>1)&3).
// 1-D grid, XCD-aware raster keeps each A row-stripe in one XCD's L2.
template <int NTW, int NCOL, int KSPLIT, bool RESID, bool OUT32, bool OUT16, int MINW>
__global__ __launch_bounds__(256, MINW)
void gemm_db(const u16* __restrict__ A, const u16* __restrict__ Bt,
             const float* __restrict__ bias, int K, int N,
             const float* resid, float* C32, u16* __restrict__ C16,
             u16* __restrict__ C16b, u16* __restrict__ C16c) {
  __shared__ __align__(16) u16 As[2][128 * 32];
  __shared__ __align__(16) u16 Bs[2][NTW * 1024];
  const int tid = threadIdx.x;
  const int wave = tid >> 6, lane = tid & 63;
  const int l15 = lane & 15, quad = lane >> 4;
  const int wm = wave >> 1, wn = wave & 1;

  int lin = blockIdx.x;
  int kh = 0;
  if constexpr (KSPLIT > 1) {
    const int nblk = (M_ / 128) * NCOL;
    kh = lin / nblk;
    lin -= kh * nblk;
  }
  const int rpx = (M_ / 128) / 8;              // row tiles per XCD
  const int xcd = lin & 7, local = lin >> 3;
  const int row0 = (xcd * rpx + local / NCOL) * 128;
  const int col0 = (local % NCOL) * (NTW * 32);
  const int klen = K / KSPLIT;
  const int kstart = kh * klen;

  f32x4 acc[4][NTW];
#pragma unroll
  for (int i = 0; i < 4; i++)
#pragma unroll
    for (int j = 0; j < NTW; j++) acc[i][j] = (f32x4){0.f, 0.f, 0.f, 0.f};

  const int lr = lane >> 2;
  const int lc = ((lane & 3) ^ ((lane >> 3) & 3)) * 8;  // swizzled source granule
  const u16* aG0 = A + (size_t)(row0 + (wave * 2) * 16 + lr) * K + lc;
  const u16* aG1 = A + (size_t)(row0 + (wave * 2 + 1) * 16 + lr) * K + lc;
  const int aO0 = (wave * 2) * 512 + lane * 8;
  const int aO1 = (wave * 2 + 1) * 512 + lane * 8;
  const u16* bG[NTW / 2];
  int bO[NTW / 2];
#pragma unroll
  for (int i = 0; i < NTW / 2; i++) {
    int ch = wave * (NTW / 2) + i;
    bG[i] = Bt + (size_t)(col0 + ch * 16 + lr) * K + lc;
    bO[i] = ch * 512 + lane * 8;
  }
  const int rsw = (l15 >> 1) & 3;  // frag-read swizzle term

  auto issue = [&](int kof, int buf) {
    gld16(aG0 + kof, &As[buf][aO0]);
    gld16(aG1 + kof, &As[buf][aO1]);
#pragma unroll
    for (int i = 0; i < NTW / 2; i++) gld16(bG[i] + kof, &Bs[buf][bO[i]]);
  };

  const int nIter = klen >> 5;   // >= 16 for all instantiations here
  issue(kstart, 0);
  __syncthreads();

  for (int it = 0; it < nIter; it++) {
    const int cur = it & 1;
    if (it + 1 < nIter) issue(kstart + ((it + 1) << 5), cur ^ 1);
    bf16x8 af[4], bf[NTW];
#pragma unroll
    for (int mt = 0; mt < 4; mt++)
      af[mt] = ldfrag(&As[cur][(wm * 64 + mt * 16 + l15) * 32 + ((quad ^ rsw) * 8)]);
#pragma unroll
    for (int nt = 0; nt < NTW; nt++)
      bf[nt] = ldfrag(&Bs[cur][(wn * (NTW * 16) + nt * 16 + l15) * 32 + ((quad ^ rsw) * 8)]);
#pragma unroll
    for (int mt = 0; mt < 4; mt++)
#pragma unroll
      for (int nt = 0; nt < NTW; nt++)
        acc[mt][nt] = __builtin_amdgcn_mfma_f32_16x16x32_bf16(af[mt], bf[nt], acc[mt][nt], 0, 0, 0);
    __syncthreads();
  }
#pragma unroll
  for (int mt = 0; mt < 4; mt++)
#pragma unroll
    for (int nt = 0; nt < NTW; nt++) {
      int n = col0 + wn * (NTW * 16) + nt * 16 + l15;
      float bv = (kh == 0) ? bias[n] : 0.f;
#pragma unroll
      for (int r = 0; r < 4; r++) {
        int m = row0 + wm * 64 + mt * 16 + quad * 4 + r;
        size_t idx = (size_t)m * N + n;
        float val = acc[mt][nt][r] + bv;
        if constexpr (KSPLIT == 4) {
          if (kh == 0)      C32[idx] = val + resid[idx];
          else if (kh == 1) C16[idx] = f2bf(val);
          else if (kh == 2) C16b[idx] = f2bf(val);
          else              C16c[idx] = f2bf(val);
        } else {
          if constexpr (RESID) val += resid[idx];
          if constexpr (OUT32) C32[idx] = val;
          if constexpr (OUT16) C16[idx] = f2bf(val);
        }
      }
    }
}

// ---------------- transpose V head-wise: vt[b,h,d,s] ----------------------
__global__ __launch_bounds__(256)
void vtrans(const u16* __restrict__ qkv, u16* __restrict__ vt) {
  __shared__ u16 t[64][65];
  int s0 = blockIdx.x * 64, h = blockIdx.y, b = blockIdx.z;
  int x = threadIdx.x, y = threadIdx.y;  // (64,4)
  const u16* src = qkv + (size_t)(b * 2048 + s0) * 1536 + 1024 + h * 64;
#pragma unroll
  for (int r = 0; r < 16; r++) { int s = y + 4*r; t[s][x] = src[(size_t)s * 1536 + x]; }
  __syncthreads();
  u16* dst = vt + (size_t)((b * 8 + h) * 64) * 2048 + s0;
#pragma unroll
  for (int r = 0; r < 16; r++) { int d = y + 4*r; dst[(size_t)d * 2048 + x] = t[x][d]; }
}

// ---------------- attention: block = (b, h, 128 q-rows) -------------------
#define PSTR 136
__global__ __launch_bounds__(256)
void attn_k(const u16* __restrict__ qkv, const u16* __restrict__ vt,
            const float* __restrict__ hres, float* __restrict__ attn) {
  __shared__ __align__(16) u16 smem[8192 + 8192 + 128 * PSTR];
  u16* Ks = smem;
  u16* Vts = smem + 8192;
  u16* Ps = smem + 16384;
  u16* Qs = Ps;

  const int lin = blockIdx.x;
  const int xcd = lin & 7, g = lin >> 3;
  const int c = g & 15;                 // 128-row q chunk
  const int bh = xcd * 4 + (g >> 4);    // (b,h) pinned to xcd
  const int hh = bh & 7, b = bh >> 3;
  const int s0 = c * 128;
  const int tid = threadIdx.x, wave = tid >> 6, lane = tid & 63;
  const int l15 = lane & 15, quad = lane >> 4;
  const int t_lo = (c > 4) ? c - 4 : 0;
  const int t_hi = (c + 2 < 16) ? c + 2 : 16;
  const int l7sw = l15 & 7;

  // stage Q (128x64), swizzled
  {
    const int cg = ((lane & 7) ^ (lane >> 3)) * 8;
    const int cp = (lane & 7) * 8;
#pragma unroll
    for (int q2 = 0; q2 < 4; q2++) {
      int r = wave * 32 + q2 * 8 + (lane >> 3);
      gld16(qkv + (size_t)(b * 2048 + s0 + r) * 1536 + hh * 64 + cg, Qs + r * 64 + cp);
    }
  }
  __syncthreads();
  bf16x8 qf[2][2];
#pragma unroll
  for (int qg = 0; qg < 2; qg++)
#pragma unroll
    for (int f = 0; f < 2; f++)
      qf[qg][f] = ldfrag(Qs + (qg * 64 + wave * 16 + l15) * 64 + (((f * 4 + quad) ^ l7sw) * 8));

  const u16x8 ones16 = {0x3F80, 0x3F80, 0x3F80, 0x3F80, 0x3F80, 0x3F80, 0x3F80, 0x3F80};
  const bf16x8 onesf = __builtin_bit_cast(bf16x8, ones16);

  f32x4 accO[2][4];
#pragma unroll
  for (int qg = 0; qg < 2; qg++)
#pragma unroll
    for (int i = 0; i < 4; i++) accO[qg][i] = (f32x4){0.f, 0.f, 0.f, 0.f};
  f32x4 accD[2] = {(f32x4){0.f, 0.f, 0.f, 0.f}, (f32x4){0.f, 0.f, 0.f, 0.f}};

  for (int kt = t_lo; kt < t_hi; ++kt) {
    __syncthreads();  // prior-iter reads done before restage
    {
      const int cgk = ((lane & 7) ^ (lane >> 3)) * 8;
      const int cpk = (lane & 7) * 8;
#pragma unroll
      for (int q2 = 0; q2 < 4; q2++) {  // K tile 128 rows
        int r = wave * 32 + q2 * 8 + (lane >> 3);
        gld16(qkv + (size_t)(b * 2048 + kt * 128 + r) * 1536 + 512 + hh * 64 + cgk,
              Ks + r * 64 + cpk);
      }
      const int cpv = (lane & 15) * 8;
#pragma unroll
      for (int q2 = 0; q2 < 4; q2++) {  // Vt tile 64 rows
        int d = (wave * 4 + q2) * 4 + (lane >> 4);
        int cgv = ((lane & 8) | ((lane & 7) ^ (lane >> 4) ^ ((q2 & 1) << 2))) * 8;
        gld16(vt + (size_t)((b * 8 + hh) * 64 + d) * 2048 + kt * 128 + cgv,
              Vts + d * 128 + cpv);
      }
    }
    __syncthreads();

#pragma unroll
    for (int nt = 0; nt < 8; nt++) {
      bf16x8 kf0 = ldfrag(Ks + (nt * 16 + l15) * 64 + ((quad ^ l7sw) * 8));
      bf16x8 kf1 = ldfrag(Ks + (nt * 16 + l15) * 64 + (((4 + quad) ^ l7sw) * 8));
#pragma unroll
      for (int qg = 0; qg < 2; qg++) {
        f32x4 s4 = (f32x4){0.f, 0.f, 0.f, 0.f};
        s4 = __builtin_amdgcn_mfma_f32_16x16x32_bf16(qf[qg][0], kf0, s4, 0, 0, 0);
        s4 = __builtin_amdgcn_mfma_f32_16x16x32_bf16(qf[qg][1], kf1, s4, 0, 0, 0);
#pragma unroll
        for (int r = 0; r < 4; r++) {
          float pp = exp2f(s4[r] * (1.4426950408889634f * 0.125f));  // exp(s/8)
          Ps[(qg * 64 + wave * 16 + quad * 4 + r) * PSTR + nt * 16 + l15] =
              (u16)(__builtin_bit_cast(uint32_t, pp) >> 16);  // truncate
        }
      }
    }
    // PV — wave reads only its own P rows, no cross-wave barrier needed
#pragma unroll
    for (int ki = 0; ki < 4; ki++) {
      bf16x8 pf[2];
#pragma unroll
      for (int qg = 0; qg < 2; qg++) {
        pf[qg] = ldfrag(Ps + (qg * 64 + wave * 16 + l15) * PSTR + (ki * 4 + quad) * 8);
        accD[qg] = __builtin_amdgcn_mfma_f32_16x16x32_bf16(pf[qg], onesf, accD[qg], 0, 0, 0);
      }
#pragma unroll
      for (int dt = 0; dt < 4; dt++) {
        int gg = ki * 4 + quad;
        bf16x8 vf = ldfrag(Vts + (dt * 16 + l15) * 128 + (((gg & 8) | ((gg & 7) ^ l7sw)) * 8));
#pragma unroll
        for (int qg = 0; qg < 2; qg++)
          accO[qg][dt] = __builtin_amdgcn_mfma_f32_16x16x32_bf16(pf[qg], vf, accO[qg][dt], 0, 0, 0);
      }
    }
  }
#pragma unroll
  for (int qg = 0; qg < 2; qg++)
#pragma unroll
    for (int r = 0; r < 4; r++) {
      float dinv = 1.0f / accD[qg][r];
      int m = s0 + qg * 64 + wave * 16 + quad * 4 + r;
#pragma unroll
      for (int dt = 0; dt < 4; dt++) {
        size_t idx = (size_t)(b * 2048 + m) * 512 + hh * 64 + dt * 16 + l15;
        attn[idx] = accO[qg][dt][r] * dinv + hres[idx];
      }
    }
}

extern "C" void kernel_launch(void* const* d_in, const int* in_sizes, int n_in,
                              void* d_out, int out_size, void* d_ws, size_t ws_size,
                              hipStream_t stream) {
  (void)in_sizes; (void)n_in; (void)out_size; (void)ws_size;
  const float* x       = (const float*)d_in[0];
  const float* ln_in_g = (const float*)d_in[2];
  const float* ln_in_b = (const float*)d_in[3];
  const float* wq = (const float*)d_in[4];
  const float* bq = (const float*)d_in[5];
  const float* wk = (const float*)d_in[6];
  const float* bk = (const float*)d_in[7];
  const float* wv = (const float*)d_in[8];
  const float* bv = (const float*)d_in[9];
  const float* ln1_g = (const float*)d_in[10];
  const float* ln1_b = (const float*)d_in[11];
  const float* w1 = (const float*)d_in[12];
  const float* b1 = (const float*)d_in[13];
  const float* w2 = (const float*)d_in[14];
  const float* b2 = (const float*)d_in[15];
  const float* ln2_g = (const float*)d_in[16];
  const float* ln2_b = (const float*)d_in[17];

  char* ws = (char*)d_ws;
  size_t off = 0;
  auto alloc = [&](size_t bytes) {
    void* p = ws + off;
    off = (off + bytes + 255) & ~(size_t)255;
    return p;
  };
  u16*   wqkvt = (u16*)  alloc((size_t)1536 * 512 * 2);
  float* bqkv  = (float*)alloc(1536 * 4);
  u16*   w1t   = (u16*)  alloc((size_t)2048 * 512 * 2);
  u16*   w2t   = (u16*)  alloc((size_t)512 * 2048 * 2);
  float* h32   = (float*)alloc((size_t)M_ * 512 * 4);   // hres; later FFN2 kh2+kh3 partials
  u16*   h16   = (u16*)  alloc((size_t)M_ * 512 * 2);   // ln-in bf16 / o16 / FFN2 kh1 partial
  u16*   qkv16 = (u16*)  alloc((size_t)M_ * 1536 * 2);  // + vtb = f16b (FFN mid)
  u16*   vtb   = (u16*)  alloc((size_t)B_ * H_ * 64 * 2048 * 2);  // part of f16b span — never reused!
  float* attn32= (float*)alloc((size_t)M_ * 512 * 4);   // attn out; FFN2 kh0 in-place
  u16*   o16   = h16;
  u16*   f16b  = qkv16;  // 8192*2048*2 bytes spans qkv16+vtb exactly
  // FFN2 bf16 partials: kh1 -> h16 (free after FFN1); kh2/kh3 -> the two
  // halves of h32 (16 MB fp32 hres buffer, free after attn_k). None of
  // these alias f16b (the FFN2 A operand) — that aliasing was the r10 bug.
  u16*   p2b   = (u16*)h32;
  u16*   p3b   = (u16*)h32 + (size_t)M_ * 512;

  prep<<<dim3(2822), 256, 0, stream>>>(wq, wk, wv, w1, w2, bq, bk, bv,
                                       wqkvt, w1t, w2t, bqkv);

  ln_k<true, true, 0><<<M_, 128, 0, stream>>>(x, ln_in_g, ln_in_b, h32, h16,
                                              nullptr, nullptr, nullptr);
  // QKV: M=8192 N=1536 K=512, tile 128x64 -> 24*64 = 1536 blocks, 6 blk/CU
  gemm_db<2, 24, 1, false, false, true, 6><<<dim3(24 * 64), 256, 0, stream>>>(
      h16, wqkvt, bqkv, 512, 1536, nullptr, nullptr, qkv16, nullptr, nullptr);
  vtrans<<<dim3(32, 8, 4), dim3(64, 4), 0, stream>>>(qkv16, vtb);
  attn_k<<<dim3(512), 256, 0, stream>>>(qkv16, vtb, h32, attn32);
  ln_k<false, true, 0><<<M_, 128, 0, stream>>>(attn32, ln1_g, ln1_b, nullptr, o16,
                                               nullptr, nullptr, nullptr);
  // FFN1: M=8192 N=2048 K=512, tile 128x128 -> 16*64 = 1024 blocks, 5 blk/CU
  gemm_db<4, 16, 1, false, false, true, 5><<<dim3(16 * 64), 256, 0, stream>>>(
      o16, w1t, b1, 512, 2048, nullptr, nullptr, f16b, nullptr, nullptr);
  // FFN2: M=8192 N=512 K=2048, tile 128x128, KSPLIT=4 -> 1024 blocks, 5 blk/CU
  gemm_db<4, 4, 4, false, false, false, 5><<<dim3(4 * 4 * 64), 256, 0, stream>>>(
      f16b, w2t, b2, 2048, 512, attn32, attn32, h16, p2b, p3b);
  ln_k<true, false, 3><<<M_, 128, 0, stream>>>(attn32, ln2_g, ln2_b, (float*)d_out,
                                               nullptr, h16, p2b, p3b);
}

// Round 5
// 289.610 us; speedup vs baseline: 1.0604x; 1.0199x over previous
//
#include <hip/hip_runtime.h>
#include <stdint.h>

#define B_ 4
#define S_ 2048
#define D_ 512
#define H_ 8
#define FFN_ 2048
#define M_ (B_*S_)

typedef unsigned short u16;
typedef __attribute__((ext_vector_type(8))) __bf16 bf16x8;
typedef __attribute__((ext_vector_type(8))) u16 u16x8;
typedef __attribute__((ext_vector_type(4))) u16 u16x4;
typedef __attribute__((ext_vector_type(4))) float f32x4;

__device__ __forceinline__ u16 f2bf(float f) {
  uint32_t u = __builtin_bit_cast(uint32_t, f);
  u += 0x7FFFu + ((u >> 16) & 1u);
  return (u16)(u >> 16);
}
__device__ __forceinline__ bf16x8 ldfrag(const u16* p) {
  return __builtin_bit_cast(bf16x8, *(const u16x8*)p);
}
__device__ __forceinline__ void gld16(const void* g, void* l) {
  __builtin_amdgcn_global_load_lds(
      (const __attribute__((address_space(1))) void*)g,
      (__attribute__((address_space(3))) void*)l, 16, 0, 0);
}

// ---------------- merged weight prep: all transposes + bias concat --------
__global__ __launch_bounds__(256)
void prep(const float* __restrict__ wq, const float* __restrict__ wk,
          const float* __restrict__ wv, const float* __restrict__ w1,
          const float* __restrict__ w2, const float* __restrict__ bq,
          const float* __restrict__ bk, const float* __restrict__ bv,
          u16* __restrict__ wqkvt, u16* __restrict__ w1t,
          u16* __restrict__ w2t, float* __restrict__ bqkv) {
  int id = blockIdx.x, tid = threadIdx.x;
  if (id >= 2816) {
    int i = (id - 2816) * 256 + tid;
    bqkv[i] = i < 512 ? bq[i] : (i < 1024 ? bk[i - 512] : bv[i - 1024]);
    return;
  }
  __shared__ float t[32][33];
  const float* W; u16* dst; int K, N, bx, by;
  if (id < 768) {
    int z = id >> 8, r = id & 255;
    W = z == 0 ? wq : (z == 1 ? wk : wv);
    dst = wqkvt + (size_t)z * 512 * 512; K = 512; N = 512;
    bx = r & 15; by = r >> 4;
  } else if (id < 1792) {
    int r = id - 768; W = w1; dst = w1t; K = 512; N = 2048;
    bx = r & 63; by = r >> 6;
  } else {
    int r = id - 1792; W = w2; dst = w2t; K = 2048; N = 512;
    bx = r & 15; by = r >> 4;
  }
  int n0 = bx * 32, k0 = by * 32, x = tid & 31, y = tid >> 5;
#pragma unroll
  for (int r = 0; r < 4; r++) t[y + 8*r][x] = W[(size_t)(k0 + y + 8*r) * N + n0 + x];
  __syncthreads();
#pragma unroll
  for (int r = 0; r < 4; r++) dst[(size_t)(n0 + y + 8*r) * K + k0 + x] = f2bf(t[x][y + 8*r]);
}

// ---------------- layernorm over rows of 512 ------------------------------
// NX = number of bf16 partial arrays to add to x (split-K combine fused)
template <bool OUT32, bool OUT16, int NX>
__global__ __launch_bounds__(128)
void ln_k(const float* __restrict__ x, const float* __restrict__ g,
          const float* __restrict__ bta, float* __restrict__ y32,
          u16* __restrict__ y16, const u16* __restrict__ p1,
          const u16* __restrict__ p2, const u16* __restrict__ p3) {
  int row = blockIdx.x;
  int t = threadIdx.x;
  const float* xr = x + (size_t)row * 512;
  f32x4 v = *(const f32x4*)(xr + t * 4);
  if constexpr (NX >= 1) {
    u16x4 a = *(const u16x4*)(p1 + (size_t)row * 512 + t * 4);
#pragma unroll
    for (int j = 0; j < 4; j++) v[j] += __builtin_bit_cast(float, (uint32_t)a[j] << 16);
  }
  if constexpr (NX >= 2) {
    u16x4 a = *(const u16x4*)(p2 + (size_t)row * 512 + t * 4);
#pragma unroll
    for (int j = 0; j < 4; j++) v[j] += __builtin_bit_cast(float, (uint32_t)a[j] << 16);
  }
  if constexpr (NX >= 3) {
    u16x4 a = *(const u16x4*)(p3 + (size_t)row * 512 + t * 4);
#pragma unroll
    for (int j = 0; j < 4; j++) v[j] += __builtin_bit_cast(float, (uint32_t)a[j] << 16);
  }
  float s = v.x + v.y + v.z + v.w;
  float s2 = v.x*v.x + v.y*v.y + v.z*v.z + v.w*v.w;
#pragma unroll
  for (int m = 32; m; m >>= 1) { s += __shfl_xor(s, m); s2 += __shfl_xor(s2, m); }
  __shared__ float p[4];
  int wv = t >> 6;
  if ((t & 63) == 0) { p[wv] = s; p[2 + wv] = s2; }
  __syncthreads();
  s = p[0] + p[1]; s2 = p[2] + p[3];
  float mean = s * (1.f / 512.f);
  float var = s2 * (1.f / 512.f) - mean * mean;
  float rs = rsqrtf(var + 1e-5f);
#pragma unroll
  for (int j = 0; j < 4; j++) {
    float o = (v[j] - mean) * rs * g[t*4 + j] + bta[t*4 + j];
    if constexpr (OUT32) y32[(size_t)row * 512 + t*4 + j] = o;
    if constexpr (OUT16) y16[(size_t)row * 512 + t*4 + j] = f2bf(o);
  }
}

// ---------------- GEMM: C[M,N] = A[M,K](bf16) @ Wt[N,K]^T + bias ----------
// TLP-first structure: 2-buffer LDS, ONE __syncthreads per K-iter
// (stage next tile -> ds_read current -> MFMA -> barrier; compiler-managed
// waitcnts, no inline asm). ALL GEMMs use NTW=2 (128x64 tile, 24 KiB LDS)
// -> 6 blocks/CU (24 waves), with grids sized >= 6 per CU. Rationale
// (r0-r3 post-mortem): per-block-iter duty is pinned ~6% by un-removable
// latency drains; duration tracks resident blocks/CU monotonically and
// nothing else; r3's FFN1/FFN2 were grid-capped at 4/CU (1024 blocks) —
// this round uncaps them (2048-block grids, LDS-capped at 6/CU).
// KSPLIT=4: kh0 -> fp32 + bias + resid (in-place safe: one thread per elem);
// kh1/2/3 -> bf16 partials to C16/C16b/C16c (combined in ln_k<NX=3>).
// Partial buffers MUST NOT alias the A operand (r10 bug).
// LDS swizzle: granule c of row r stored at c ^ ((r>>1)&3).
// 1-D grid, XCD-aware raster keeps each A row-stripe in one XCD's L2.
template <int NTW, int NCOL, int KSPLIT, bool RESID, bool OUT32, bool OUT16, int MINW>
__global__ __launch_bounds__(256, MINW)
void gemm_db(const u16* __restrict__ A, const u16* __restrict__ Bt,
             const float* __restrict__ bias, int K, int N,
             const float* resid, float* C32, u16* __restrict__ C16,
             u16* __restrict__ C16b, u16* __restrict__ C16c) {
  __shared__ __align__(16) u16 As[2][128 * 32];
  __shared__ __align__(16) u16 Bs[2][NTW * 1024];
  const int tid = threadIdx.x;
  const int wave = tid >> 6, lane = tid & 63;
  const int l15 = lane & 15, quad = lane >> 4;
  const int wm = wave >> 1, wn = wave & 1;

  int lin = blockIdx.x;
  int kh = 0;
  if constexpr (KSPLIT > 1) {
    const int nblk = (M_ / 128) * NCOL;
    kh = lin / nblk;
    lin -= kh * nblk;
  }
  const int rpx = (M_ / 128) / 8;              // row tiles per XCD
  const int xcd = lin & 7, local = lin >> 3;
  const int row0 = (xcd * rpx + local / NCOL) * 128;
  const int col0 = (local % NCOL) * (NTW * 32);
  const int klen = K / KSPLIT;
  const int kstart = kh * klen;

  f32x4 acc[4][NTW];
#pragma unroll
  for (int i = 0; i < 4; i++)
#pragma unroll
    for (int j = 0; j < NTW; j++) acc[i][j] = (f32x4){0.f, 0.f, 0.f, 0.f};

  const int lr = lane >> 2;
  const int lc = ((lane & 3) ^ ((lane >> 3) & 3)) * 8;  // swizzled source granule
  const u16* aG0 = A + (size_t)(row0 + (wave * 2) * 16 + lr) * K + lc;
  const u16* aG1 = A + (size_t)(row0 + (wave * 2 + 1) * 16 + lr) * K + lc;
  const int aO0 = (wave * 2) * 512 + lane * 8;
  const int aO1 = (wave * 2 + 1) * 512 + lane * 8;
  const u16* bG[NTW / 2];
  int bO[NTW / 2];
#pragma unroll
  for (int i = 0; i < NTW / 2; i++) {
    int ch = wave * (NTW / 2) + i;
    bG[i] = Bt + (size_t)(col0 + ch * 16 + lr) * K + lc;
    bO[i] = ch * 512 + lane * 8;
  }
  const int rsw = (l15 >> 1) & 3;  // frag-read swizzle term

  auto issue = [&](int kof, int buf) {
    gld16(aG0 + kof, &As[buf][aO0]);
    gld16(aG1 + kof, &As[buf][aO1]);
#pragma unroll
    for (int i = 0; i < NTW / 2; i++) gld16(bG[i] + kof, &Bs[buf][bO[i]]);
  };

  const int nIter = klen >> 5;   // >= 16 for all instantiations here
  issue(kstart, 0);
  __syncthreads();

  for (int it = 0; it < nIter; it++) {
    const int cur = it & 1;
    if (it + 1 < nIter) issue(kstart + ((it + 1) << 5), cur ^ 1);
    bf16x8 af[4], bf[NTW];
#pragma unroll
    for (int mt = 0; mt < 4; mt++)
      af[mt] = ldfrag(&As[cur][(wm * 64 + mt * 16 + l15) * 32 + ((quad ^ rsw) * 8)]);
#pragma unroll
    for (int nt = 0; nt < NTW; nt++)
      bf[nt] = ldfrag(&Bs[cur][(wn * (NTW * 16) + nt * 16 + l15) * 32 + ((quad ^ rsw) * 8)]);
#pragma unroll
    for (int mt = 0; mt < 4; mt++)
#pragma unroll
      for (int nt = 0; nt < NTW; nt++)
        acc[mt][nt] = __builtin_amdgcn_mfma_f32_16x16x32_bf16(af[mt], bf[nt], acc[mt][nt], 0, 0, 0);
    __syncthreads();
  }
#pragma unroll
  for (int mt = 0; mt < 4; mt++)
#pragma unroll
    for (int nt = 0; nt < NTW; nt++) {
      int n = col0 + wn * (NTW * 16) + nt * 16 + l15;
      float bv = (kh == 0) ? bias[n] : 0.f;
#pragma unroll
      for (int r = 0; r < 4; r++) {
        int m = row0 + wm * 64 + mt * 16 + quad * 4 + r;
        size_t idx = (size_t)m * N + n;
        float val = acc[mt][nt][r] + bv;
        if constexpr (KSPLIT == 4) {
          if (kh == 0)      C32[idx] = val + resid[idx];
          else if (kh == 1) C16[idx] = f2bf(val);
          else if (kh == 2) C16b[idx] = f2bf(val);
          else              C16c[idx] = f2bf(val);
        } else {
          if constexpr (RESID) val += resid[idx];
          if constexpr (OUT32) C32[idx] = val;
          if constexpr (OUT16) C16[idx] = f2bf(val);
        }
      }
    }
}

// ---------------- transpose V head-wise: vt[b,h,d,s] ----------------------
__global__ __launch_bounds__(256)
void vtrans(const u16* __restrict__ qkv, u16* __restrict__ vt) {
  __shared__ u16 t[64][65];
  int s0 = blockIdx.x * 64, h = blockIdx.y, b = blockIdx.z;
  int x = threadIdx.x, y = threadIdx.y;  // (64,4)
  const u16* src = qkv + (size_t)(b * 2048 + s0) * 1536 + 1024 + h * 64;
#pragma unroll
  for (int r = 0; r < 16; r++) { int s = y + 4*r; t[s][x] = src[(size_t)s * 1536 + x]; }
  __syncthreads();
  u16* dst = vt + (size_t)((b * 8 + h) * 64) * 2048 + s0;
#pragma unroll
  for (int r = 0; r < 16; r++) { int d = y + 4*r; dst[(size_t)d * 2048 + x] = t[x][d]; }
}

// ---------------- attention: block = (b, h, 128 q-rows) -------------------
#define PSTR 136
__global__ __launch_bounds__(256)
void attn_k(const u16* __restrict__ qkv, const u16* __restrict__ vt,
            const float* __restrict__ hres, float* __restrict__ attn) {
  __shared__ __align__(16) u16 smem[8192 + 8192 + 128 * PSTR];
  u16* Ks = smem;
  u16* Vts = smem + 8192;
  u16* Ps = smem + 16384;
  u16* Qs = Ps;

  const int lin = blockIdx.x;
  const int xcd = lin & 7, g = lin >> 3;
  const int c = g & 15;                 // 128-row q chunk
  const int bh = xcd * 4 + (g >> 4);    // (b,h) pinned to xcd
  const int hh = bh & 7, b = bh >> 3;
  const int s0 = c * 128;
  const int tid = threadIdx.x, wave = tid >> 6, lane = tid & 63;
  const int l15 = lane & 15, quad = lane >> 4;
  const int t_lo = (c > 4) ? c - 4 : 0;
  const int t_hi = (c + 2 < 16) ? c + 2 : 16;
  const int l7sw = l15 & 7;

  // stage Q (128x64), swizzled
  {
    const int cg = ((lane & 7) ^ (lane >> 3)) * 8;
    const int cp = (lane & 7) * 8;
#pragma unroll
    for (int q2 = 0; q2 < 4; q2++) {
      int r = wave * 32 + q2 * 8 + (lane >> 3);
      gld16(qkv + (size_t)(b * 2048 + s0 + r) * 1536 + hh * 64 + cg, Qs + r * 64 + cp);
    }
  }
  __syncthreads();
  bf16x8 qf[2][2];
#pragma unroll
  for (int qg = 0; qg < 2; qg++)
#pragma unroll
    for (int f = 0; f < 2; f++)
      qf[qg][f] = ldfrag(Qs + (qg * 64 + wave * 16 + l15) * 64 + (((f * 4 + quad) ^ l7sw) * 8));

  const u16x8 ones16 = {0x3F80, 0x3F80, 0x3F80, 0x3F80, 0x3F80, 0x3F80, 0x3F80, 0x3F80};
  const bf16x8 onesf = __builtin_bit_cast(bf16x8, ones16);

  f32x4 accO[2][4];
#pragma unroll
  for (int qg = 0; qg < 2; qg++)
#pragma unroll
    for (int i = 0; i < 4; i++) accO[qg][i] = (f32x4){0.f, 0.f, 0.f, 0.f};
  f32x4 accD[2] = {(f32x4){0.f, 0.f, 0.f, 0.f}, (f32x4){0.f, 0.f, 0.f, 0.f}};

  for (int kt = t_lo; kt < t_hi; ++kt) {
    __syncthreads();  // prior-iter reads done before restage
    {
      const int cgk = ((lane & 7) ^ (lane >> 3)) * 8;
      const int cpk = (lane & 7) * 8;
#pragma unroll
      for (int q2 = 0; q2 < 4; q2++) {  // K tile 128 rows
        int r = wave * 32 + q2 * 8 + (lane >> 3);
        gld16(qkv + (size_t)(b * 2048 + kt * 128 + r) * 1536 + 512 + hh * 64 + cgk,
              Ks + r * 64 + cpk);
      }
      const int cpv = (lane & 15) * 8;
#pragma unroll
      for (int q2 = 0; q2 < 4; q2++) {  // Vt tile 64 rows
        int d = (wave * 4 + q2) * 4 + (lane >> 4);
        int cgv = ((lane & 8) | ((lane & 7) ^ (lane >> 4) ^ ((q2 & 1) << 2))) * 8;
        gld16(vt + (size_t)((b * 8 + hh) * 64 + d) * 2048 + kt * 128 + cgv,
              Vts + d * 128 + cpv);
      }
    }
    __syncthreads();

#pragma unroll
    for (int nt = 0; nt < 8; nt++) {
      bf16x8 kf0 = ldfrag(Ks + (nt * 16 + l15) * 64 + ((quad ^ l7sw) * 8));
      bf16x8 kf1 = ldfrag(Ks + (nt * 16 + l15) * 64 + (((4 + quad) ^ l7sw) * 8));
#pragma unroll
      for (int qg = 0; qg < 2; qg++) {
        f32x4 s4 = (f32x4){0.f, 0.f, 0.f, 0.f};
        s4 = __builtin_amdgcn_mfma_f32_16x16x32_bf16(qf[qg][0], kf0, s4, 0, 0, 0);
        s4 = __builtin_amdgcn_mfma_f32_16x16x32_bf16(qf[qg][1], kf1, s4, 0, 0, 0);
#pragma unroll
        for (int r = 0; r < 4; r++) {
          float pp = exp2f(s4[r] * (1.4426950408889634f * 0.125f));  // exp(s/8)
          Ps[(qg * 64 + wave * 16 + quad * 4 + r) * PSTR + nt * 16 + l15] =
              (u16)(__builtin_bit_cast(uint32_t, pp) >> 16);  // truncate
        }
      }
    }
    // PV — wave reads only its own P rows, no cross-wave barrier needed
#pragma unroll
    for (int ki = 0; ki < 4; ki++) {
      bf16x8 pf[2];
#pragma unroll
      for (int qg = 0; qg < 2; qg++) {
        pf[qg] = ldfrag(Ps + (qg * 64 + wave * 16 + l15) * PSTR + (ki * 4 + quad) * 8);
        accD[qg] = __builtin_amdgcn_mfma_f32_16x16x32_bf16(pf[qg], onesf, accD[qg], 0, 0, 0);
      }
#pragma unroll
      for (int dt = 0; dt < 4; dt++) {
        int gg = ki * 4 + quad;
        bf16x8 vf = ldfrag(Vts + (dt * 16 + l15) * 128 + (((gg & 8) | ((gg & 7) ^ l7sw)) * 8));
#pragma unroll
        for (int qg = 0; qg < 2; qg++)
          accO[qg][dt] = __builtin_amdgcn_mfma_f32_16x16x32_bf16(pf[qg], vf, accO[qg][dt], 0, 0, 0);
      }
    }
  }
#pragma unroll
  for (int qg = 0; qg < 2; qg++)
#pragma unroll
    for (int r = 0; r < 4; r++) {
      float dinv = 1.0f / accD[qg][r];
      int m = s0 + qg * 64 + wave * 16 + quad * 4 + r;
#pragma unroll
      for (int dt = 0; dt < 4; dt++) {
        size_t idx = (size_t)(b * 2048 + m) * 512 + hh * 64 + dt * 16 + l15;
        attn[idx] = accO[qg][dt][r] * dinv + hres[idx];
      }
    }
}

extern "C" void kernel_launch(void* const* d_in, const int* in_sizes, int n_in,
                              void* d_out, int out_size, void* d_ws, size_t ws_size,
                              hipStream_t stream) {
  (void)in_sizes; (void)n_in; (void)out_size; (void)ws_size;
  const float* x       = (const float*)d_in[0];
  const float* ln_in_g = (const float*)d_in[2];
  const float* ln_in_b = (const float*)d_in[3];
  const float* wq = (const float*)d_in[4];
  const float* bq = (const float*)d_in[5];
  const float* wk = (const float*)d_in[6];
  const float* bk = (const float*)d_in[7];
  const float* wv = (const float*)d_in[8];
  const float* bv = (const float*)d_in[9];
  const float* ln1_g = (const float*)d_in[10];
  const float* ln1_b = (const float*)d_in[11];
  const float* w1 = (const float*)d_in[12];
  const float* b1 = (const float*)d_in[13];
  const float* w2 = (const float*)d_in[14];
  const float* b2 = (const float*)d_in[15];
  const float* ln2_g = (const float*)d_in[16];
  const float* ln2_b = (const float*)d_in[17];

  char* ws = (char*)d_ws;
  size_t off = 0;
  auto alloc = [&](size_t bytes) {
    void* p = ws + off;
    off = (off + bytes + 255) & ~(size_t)255;
    return p;
  };
  u16*   wqkvt = (u16*)  alloc((size_t)1536 * 512 * 2);
  float* bqkv  = (float*)alloc(1536 * 4);
  u16*   w1t   = (u16*)  alloc((size_t)2048 * 512 * 2);
  u16*   w2t   = (u16*)  alloc((size_t)512 * 2048 * 2);
  float* h32   = (float*)alloc((size_t)M_ * 512 * 4);   // hres; later FFN2 kh2+kh3 partials
  u16*   h16   = (u16*)  alloc((size_t)M_ * 512 * 2);   // ln-in bf16 / o16 / FFN2 kh1 partial
  u16*   qkv16 = (u16*)  alloc((size_t)M_ * 1536 * 2);  // + vtb = f16b (FFN mid)
  u16*   vtb   = (u16*)  alloc((size_t)B_ * H_ * 64 * 2048 * 2);  // part of f16b span — never reused!
  float* attn32= (float*)alloc((size_t)M_ * 512 * 4);   // attn out; FFN2 kh0 in-place
  u16*   o16   = h16;
  u16*   f16b  = qkv16;  // 8192*2048*2 bytes spans qkv16+vtb exactly
  // FFN2 bf16 partials: kh1 -> h16 (free after FFN1); kh2/kh3 -> the two
  // halves of h32 (16 MB fp32 hres buffer, free after attn_k). None of
  // these alias f16b (the FFN2 A operand) — that aliasing was the r10 bug.
  u16*   p2b   = (u16*)h32;
  u16*   p3b   = (u16*)h32 + (size_t)M_ * 512;

  prep<<<dim3(2822), 256, 0, stream>>>(wq, wk, wv, w1, w2, bq, bk, bv,
                                       wqkvt, w1t, w2t, bqkv);

  ln_k<true, true, 0><<<M_, 128, 0, stream>>>(x, ln_in_g, ln_in_b, h32, h16,
                                              nullptr, nullptr, nullptr);
  // QKV: M=8192 N=1536 K=512, tile 128x64 -> 24*64 = 1536 blocks, 6 blk/CU
  gemm_db<2, 24, 1, false, false, true, 6><<<dim3(24 * 64), 256, 0, stream>>>(
      h16, wqkvt, bqkv, 512, 1536, nullptr, nullptr, qkv16, nullptr, nullptr);
  vtrans<<<dim3(32, 8, 4), dim3(64, 4), 0, stream>>>(qkv16, vtb);
  attn_k<<<dim3(512), 256, 0, stream>>>(qkv16, vtb, h32, attn32);
  ln_k<false, true, 0><<<M_, 128, 0, stream>>>(attn32, ln1_g, ln1_b, nullptr, o16,
                                               nullptr, nullptr, nullptr);
  // FFN1: M=8192 N=2048 K=512, tile 128x64 -> 32*64 = 2048 blocks, 6 blk/CU (LDS-capped)
  gemm_db<2, 32, 1, false, false, true, 6><<<dim3(32 * 64), 256, 0, stream>>>(
      o16, w1t, b1, 512, 2048, nullptr, nullptr, f16b, nullptr, nullptr);
  // FFN2: M=8192 N=512 K=2048, tile 128x64, KSPLIT=4 -> 4*8*64 = 2048 blocks, 6 blk/CU
  gemm_db<2, 8, 4, false, false, false, 6><<<dim3(4 * 8 * 64), 256, 0, stream>>>(
      f16b, w2t, b2, 2048, 512, attn32, attn32, h16, p2b, p3b);
  ln_k<true, false, 3><<<M_, 128, 0, stream>>>(attn32, ln2_g, ln2_b, (float*)d_out,
                                               nullptr, h16, p2b, p3b);
}

// Round 6
// 283.617 us; speedup vs baseline: 1.0828x; 1.0211x over previous
//
#include <hip/hip_runtime.h>
#include <stdint.h>

#define B_ 4
#define S_ 2048
#define D_ 512
#define H_ 8
#define FFN_ 2048
#define M_ (B_*S_)

typedef unsigned short u16;
typedef __attribute__((ext_vector_type(8))) __bf16 bf16x8;
typedef __attribute__((ext_vector_type(8))) u16 u16x8;
typedef __attribute__((ext_vector_type(4))) u16 u16x4;
typedef __attribute__((ext_vector_type(4))) float f32x4;

__device__ __forceinline__ u16 f2bf(float f) {
  uint32_t u = __builtin_bit_cast(uint32_t, f);
  u += 0x7FFFu + ((u >> 16) & 1u);
  return (u16)(u >> 16);
}
__device__ __forceinline__ bf16x8 ldfrag(const u16* p) {
  return __builtin_bit_cast(bf16x8, *(const u16x8*)p);
}
__device__ __forceinline__ void gld16(const void* g, void* l) {
  __builtin_amdgcn_global_load_lds(
      (const __attribute__((address_space(1))) void*)g,
      (__attribute__((address_space(3))) void*)l, 16, 0, 0);
}

// ---------------- merged weight prep: all transposes + bias concat --------
__global__ __launch_bounds__(256)
void prep(const float* __restrict__ wq, const float* __restrict__ wk,
          const float* __restrict__ wv, const float* __restrict__ w1,
          const float* __restrict__ w2, const float* __restrict__ bq,
          const float* __restrict__ bk, const float* __restrict__ bv,
          u16* __restrict__ wqkvt, u16* __restrict__ w1t,
          u16* __restrict__ w2t, float* __restrict__ bqkv) {
  int id = blockIdx.x, tid = threadIdx.x;
  if (id >= 2816) {
    int i = (id - 2816) * 256 + tid;
    bqkv[i] = i < 512 ? bq[i] : (i < 1024 ? bk[i - 512] : bv[i - 1024]);
    return;
  }
  __shared__ float t[32][33];
  const float* W; u16* dst; int K, N, bx, by;
  if (id < 768) {
    int z = id >> 8, r = id & 255;
    W = z == 0 ? wq : (z == 1 ? wk : wv);
    dst = wqkvt + (size_t)z * 512 * 512; K = 512; N = 512;
    bx = r & 15; by = r >> 4;
  } else if (id < 1792) {
    int r = id - 768; W = w1; dst = w1t; K = 512; N = 2048;
    bx = r & 63; by = r >> 6;
  } else {
    int r = id - 1792; W = w2; dst = w2t; K = 2048; N = 512;
    bx = r & 15; by = r >> 4;
  }
  int n0 = bx * 32, k0 = by * 32, x = tid & 31, y = tid >> 5;
#pragma unroll
  for (int r = 0; r < 4; r++) t[y + 8*r][x] = W[(size_t)(k0 + y + 8*r) * N + n0 + x];
  __syncthreads();
#pragma unroll
  for (int r = 0; r < 4; r++) dst[(size_t)(n0 + y + 8*r) * K + k0 + x] = f2bf(t[x][y + 8*r]);
}

// ---------------- layernorm over rows of 512 ------------------------------
// NX = number of bf16 partial arrays to add to x (split-K combine fused)
template <bool OUT32, bool OUT16, int NX>
__global__ __launch_bounds__(128)
void ln_k(const float* __restrict__ x, const float* __restrict__ g,
          const float* __restrict__ bta, float* __restrict__ y32,
          u16* __restrict__ y16, const u16* __restrict__ p1,
          const u16* __restrict__ p2, const u16* __restrict__ p3) {
  int row = blockIdx.x;
  int t = threadIdx.x;
  const float* xr = x + (size_t)row * 512;
  f32x4 v = *(const f32x4*)(xr + t * 4);
  if constexpr (NX >= 1) {
    u16x4 a = *(const u16x4*)(p1 + (size_t)row * 512 + t * 4);
#pragma unroll
    for (int j = 0; j < 4; j++) v[j] += __builtin_bit_cast(float, (uint32_t)a[j] << 16);
  }
  if constexpr (NX >= 2) {
    u16x4 a = *(const u16x4*)(p2 + (size_t)row * 512 + t * 4);
#pragma unroll
    for (int j = 0; j < 4; j++) v[j] += __builtin_bit_cast(float, (uint32_t)a[j] << 16);
  }
  if constexpr (NX >= 3) {
    u16x4 a = *(const u16x4*)(p3 + (size_t)row * 512 + t * 4);
#pragma unroll
    for (int j = 0; j < 4; j++) v[j] += __builtin_bit_cast(float, (uint32_t)a[j] << 16);
  }
  float s = v.x + v.y + v.z + v.w;
  float s2 = v.x*v.x + v.y*v.y + v.z*v.z + v.w*v.w;
#pragma unroll
  for (int m = 32; m; m >>= 1) { s += __shfl_xor(s, m); s2 += __shfl_xor(s2, m); }
  __shared__ float p[4];
  int wv = t >> 6;
  if ((t & 63) == 0) { p[wv] = s; p[2 + wv] = s2; }
  __syncthreads();
  s = p[0] + p[1]; s2 = p[2] + p[3];
  float mean = s * (1.f / 512.f);
  float var = s2 * (1.f / 512.f) - mean * mean;
  float rs = rsqrtf(var + 1e-5f);
#pragma unroll
  for (int j = 0; j < 4; j++) {
    float o = (v[j] - mean) * rs * g[t*4 + j] + bta[t*4 + j];
    if constexpr (OUT32) y32[(size_t)row * 512 + t*4 + j] = o;
    if constexpr (OUT16) y16[(size_t)row * 512 + t*4 + j] = f2bf(o);
  }
}

// ---------------- GEMM: C[M,N] = A[M,K](bf16) @ Wt[N,K]^T + bias ----------
// 2-buffer LDS, ONE __syncthreads per K-iter (stage next -> ds_read cur ->
// MFMA -> barrier; compiler-managed waits). NTW=2: 24 KiB / 72 VGPR ->
// 4 blk/CU (VGPR-capped); NTW=4: 32 KiB / ~112 VGPR -> 4 blk/CU.
// r0-r5 model: t_CU = iters*T_iter + blocks*C0 with C0 ~ output-tile bytes
// (epilogue scatter + resid latency) ~= 50% of time at K=512. Fix here:
// OPERAND-SWAPPED MFMA -> transposed C/D mapping. mfma(bf, af): output
// m = ...+l15, n = ...+quad*4+r, so each thread owns 4 CONSECUTIVE n ->
// epilogue is one f32x4/u16x4 store per acc tile (16 full cachelines per
// wave-store), resid/bias become f32x4 loads. 4x fewer epilogue mem insts.
// KSPLIT=4: kh0 -> fp32 + bias + resid (in-place safe: one thread per 16B);
// kh1/2/3 -> bf16 partials to C16/C16b/C16c (combined in ln_k<NX=3>).
// Partial buffers MUST NOT alias the A operand (r10 bug).
// LDS swizzle: granule c of row r stored at c ^ ((r>>1)&3).
// 1-D grid, XCD-aware raster keeps each A row-stripe in one XCD's L2.
template <int NTW, int NCOL, int KSPLIT, bool RESID, bool OUT32, bool OUT16, int MINW>
__global__ __launch_bounds__(256, MINW)
void gemm_db(const u16* __restrict__ A, const u16* __restrict__ Bt,
             const float* __restrict__ bias, int K, int N,
             const float* resid, float* C32, u16* __restrict__ C16,
             u16* __restrict__ C16b, u16* __restrict__ C16c) {
  __shared__ __align__(16) u16 As[2][128 * 32];
  __shared__ __align__(16) u16 Bs[2][NTW * 1024];
  const int tid = threadIdx.x;
  const int wave = tid >> 6, lane = tid & 63;
  const int l15 = lane & 15, quad = lane >> 4;
  const int wm = wave >> 1, wn = wave & 1;

  int lin = blockIdx.x;
  int kh = 0;
  if constexpr (KSPLIT > 1) {
    const int nblk = (M_ / 128) * NCOL;
    kh = lin / nblk;
    lin -= kh * nblk;
  }
  const int rpx = (M_ / 128) / 8;              // row tiles per XCD
  const int xcd = lin & 7, local = lin >> 3;
  const int row0 = (xcd * rpx + local / NCOL) * 128;
  const int col0 = (local % NCOL) * (NTW * 32);
  const int klen = K / KSPLIT;
  const int kstart = kh * klen;

  f32x4 acc[4][NTW];
#pragma unroll
  for (int i = 0; i < 4; i++)
#pragma unroll
    for (int j = 0; j < NTW; j++) acc[i][j] = (f32x4){0.f, 0.f, 0.f, 0.f};

  const int lr = lane >> 2;
  const int lc = ((lane & 3) ^ ((lane >> 3) & 3)) * 8;  // swizzled source granule
  const u16* aG0 = A + (size_t)(row0 + (wave * 2) * 16 + lr) * K + lc;
  const u16* aG1 = A + (size_t)(row0 + (wave * 2 + 1) * 16 + lr) * K + lc;
  const int aO0 = (wave * 2) * 512 + lane * 8;
  const int aO1 = (wave * 2 + 1) * 512 + lane * 8;
  const u16* bG[NTW / 2];
  int bO[NTW / 2];
#pragma unroll
  for (int i = 0; i < NTW / 2; i++) {
    int ch = wave * (NTW / 2) + i;
    bG[i] = Bt + (size_t)(col0 + ch * 16 + lr) * K + lc;
    bO[i] = ch * 512 + lane * 8;
  }
  const int rsw = (l15 >> 1) & 3;  // frag-read swizzle term

  auto issue = [&](int kof, int buf) {
    gld16(aG0 + kof, &As[buf][aO0]);
    gld16(aG1 + kof, &As[buf][aO1]);
#pragma unroll
    for (int i = 0; i < NTW / 2; i++) gld16(bG[i] + kof, &Bs[buf][bO[i]]);
  };

  const int nIter = klen >> 5;   // >= 16 for all instantiations here
  issue(kstart, 0);
  __syncthreads();

  for (int it = 0; it < nIter; it++) {
    const int cur = it & 1;
    if (it + 1 < nIter) issue(kstart + ((it + 1) << 5), cur ^ 1);
    bf16x8 af[4], bf[NTW];
#pragma unroll
    for (int mt = 0; mt < 4; mt++)
      af[mt] = ldfrag(&As[cur][(wm * 64 + mt * 16 + l15) * 32 + ((quad ^ rsw) * 8)]);
#pragma unroll
    for (int nt = 0; nt < NTW; nt++)
      bf[nt] = ldfrag(&Bs[cur][(wn * (NTW * 16) + nt * 16 + l15) * 32 + ((quad ^ rsw) * 8)]);
    // operand-swapped: D = bf x af -> m on l15, n on quad*4+r (see header)
#pragma unroll
    for (int mt = 0; mt < 4; mt++)
#pragma unroll
      for (int nt = 0; nt < NTW; nt++)
        acc[mt][nt] = __builtin_amdgcn_mfma_f32_16x16x32_bf16(bf[nt], af[mt], acc[mt][nt], 0, 0, 0);
    __syncthreads();
  }

  // vectorized epilogue: thread owns (m = ...+l15, n = ...+quad*4 .. +3)
#pragma unroll
  for (int mt = 0; mt < 4; mt++)
#pragma unroll
    for (int nt = 0; nt < NTW; nt++) {
      const int m = row0 + wm * 64 + mt * 16 + l15;
      const int n = col0 + wn * (NTW * 16) + nt * 16 + quad * 4;
      const size_t idx = (size_t)m * N + n;
      f32x4 v4 = acc[mt][nt];
      if (kh == 0) {
        const f32x4 b4 = *(const f32x4*)(bias + n);
#pragma unroll
        for (int r = 0; r < 4; r++) v4[r] += b4[r];
      }
      if constexpr (KSPLIT == 4) {
        if (kh == 0) {
          const f32x4 rs = *(const f32x4*)(resid + idx);
#pragma unroll
          for (int r = 0; r < 4; r++) v4[r] += rs[r];
          *(f32x4*)(C32 + idx) = v4;
        } else {
          u16x4 o;
#pragma unroll
          for (int r = 0; r < 4; r++) o[r] = f2bf(v4[r]);
          u16* dst = kh == 1 ? C16 : (kh == 2 ? C16b : C16c);
          *(u16x4*)(dst + idx) = o;
        }
      } else {
        if constexpr (RESID) {
          const f32x4 rs = *(const f32x4*)(resid + idx);
#pragma unroll
          for (int r = 0; r < 4; r++) v4[r] += rs[r];
        }
        if constexpr (OUT32) *(f32x4*)(C32 + idx) = v4;
        if constexpr (OUT16) {
          u16x4 o;
#pragma unroll
          for (int r = 0; r < 4; r++) o[r] = f2bf(v4[r]);
          *(u16x4*)(C16 + idx) = o;
        }
      }
    }
}

// ---------------- transpose V head-wise: vt[b,h,d,s] ----------------------
__global__ __launch_bounds__(256)
void vtrans(const u16* __restrict__ qkv, u16* __restrict__ vt) {
  __shared__ u16 t[64][65];
  int s0 = blockIdx.x * 64, h = blockIdx.y, b = blockIdx.z;
  int x = threadIdx.x, y = threadIdx.y;  // (64,4)
  const u16* src = qkv + (size_t)(b * 2048 + s0) * 1536 + 1024 + h * 64;
#pragma unroll
  for (int r = 0; r < 16; r++) { int s = y + 4*r; t[s][x] = src[(size_t)s * 1536 + x]; }
  __syncthreads();
  u16* dst = vt + (size_t)((b * 8 + h) * 64) * 2048 + s0;
#pragma unroll
  for (int r = 0; r < 16; r++) { int d = y + 4*r; dst[(size_t)d * 2048 + x] = t[x][d]; }
}

// ---------------- attention: block = (b, h, 128 q-rows) -------------------
#define PSTR 136
__global__ __launch_bounds__(256)
void attn_k(const u16* __restrict__ qkv, const u16* __restrict__ vt,
            const float* __restrict__ hres, float* __restrict__ attn) {
  __shared__ __align__(16) u16 smem[8192 + 8192 + 128 * PSTR];
  u16* Ks = smem;
  u16* Vts = smem + 8192;
  u16* Ps = smem + 16384;
  u16* Qs = Ps;

  const int lin = blockIdx.x;
  const int xcd = lin & 7, g = lin >> 3;
  const int c = g & 15;                 // 128-row q chunk
  const int bh = xcd * 4 + (g >> 4);    // (b,h) pinned to xcd
  const int hh = bh & 7, b = bh >> 3;
  const int s0 = c * 128;
  const int tid = threadIdx.x, wave = tid >> 6, lane = tid & 63;
  const int l15 = lane & 15, quad = lane >> 4;
  const int t_lo = (c > 4) ? c - 4 : 0;
  const int t_hi = (c + 2 < 16) ? c + 2 : 16;
  const int l7sw = l15 & 7;

  // stage Q (128x64), swizzled
  {
    const int cg = ((lane & 7) ^ (lane >> 3)) * 8;
    const int cp = (lane & 7) * 8;
#pragma unroll
    for (int q2 = 0; q2 < 4; q2++) {
      int r = wave * 32 + q2 * 8 + (lane >> 3);
      gld16(qkv + (size_t)(b * 2048 + s0 + r) * 1536 + hh * 64 + cg, Qs + r * 64 + cp);
    }
  }
  __syncthreads();
  bf16x8 qf[2][2];
#pragma unroll
  for (int qg = 0; qg < 2; qg++)
#pragma unroll
    for (int f = 0; f < 2; f++)
      qf[qg][f] = ldfrag(Qs + (qg * 64 + wave * 16 + l15) * 64 + (((f * 4 + quad) ^ l7sw) * 8));

  const u16x8 ones16 = {0x3F80, 0x3F80, 0x3F80, 0x3F80, 0x3F80, 0x3F80, 0x3F80, 0x3F80};
  const bf16x8 onesf = __builtin_bit_cast(bf16x8, ones16);

  f32x4 accO[2][4];
#pragma unroll
  for (int qg = 0; qg < 2; qg++)
#pragma unroll
    for (int i = 0; i < 4; i++) accO[qg][i] = (f32x4){0.f, 0.f, 0.f, 0.f};
  f32x4 accD[2] = {(f32x4){0.f, 0.f, 0.f, 0.f}, (f32x4){0.f, 0.f, 0.f, 0.f}};

  for (int kt = t_lo; kt < t_hi; ++kt) {
    __syncthreads();  // prior-iter reads done before restage
    {
      const int cgk = ((lane & 7) ^ (lane >> 3)) * 8;
      const int cpk = (lane & 7) * 8;
#pragma unroll
      for (int q2 = 0; q2 < 4; q2++) {  // K tile 128 rows
        int r = wave * 32 + q2 * 8 + (lane >> 3);
        gld16(qkv + (size_t)(b * 2048 + kt * 128 + r) * 1536 + 512 + hh * 64 + cgk,
              Ks + r * 64 + cpk);
      }
      const int cpv = (lane & 15) * 8;
#pragma unroll
      for (int q2 = 0; q2 < 4; q2++) {  // Vt tile 64 rows
        int d = (wave * 4 + q2) * 4 + (lane >> 4);
        int cgv = ((lane & 8) | ((lane & 7) ^ (lane >> 4) ^ ((q2 & 1) << 2))) * 8;
        gld16(vt + (size_t)((b * 8 + hh) * 64 + d) * 2048 + kt * 128 + cgv,
              Vts + d * 128 + cpv);
      }
    }
    __syncthreads();

#pragma unroll
    for (int nt = 0; nt < 8; nt++) {
      bf16x8 kf0 = ldfrag(Ks + (nt * 16 + l15) * 64 + ((quad ^ l7sw) * 8));
      bf16x8 kf1 = ldfrag(Ks + (nt * 16 + l15) * 64 + (((4 + quad) ^ l7sw) * 8));
#pragma unroll
      for (int qg = 0; qg < 2; qg++) {
        f32x4 s4 = (f32x4){0.f, 0.f, 0.f, 0.f};
        s4 = __builtin_amdgcn_mfma_f32_16x16x32_bf16(qf[qg][0], kf0, s4, 0, 0, 0);
        s4 = __builtin_amdgcn_mfma_f32_16x16x32_bf16(qf[qg][1], kf1, s4, 0, 0, 0);
#pragma unroll
        for (int r = 0; r < 4; r++) {
          float pp = exp2f(s4[r] * (1.4426950408889634f * 0.125f));  // exp(s/8)
          Ps[(qg * 64 + wave * 16 + quad * 4 + r) * PSTR + nt * 16 + l15] =
              (u16)(__builtin_bit_cast(uint32_t, pp) >> 16);  // truncate
        }
      }
    }
    // PV — wave reads only its own P rows, no cross-wave barrier needed
#pragma unroll
    for (int ki = 0; ki < 4; ki++) {
      bf16x8 pf[2];
#pragma unroll
      for (int qg = 0; qg < 2; qg++) {
        pf[qg] = ldfrag(Ps + (qg * 64 + wave * 16 + l15) * PSTR + (ki * 4 + quad) * 8);
        accD[qg] = __builtin_amdgcn_mfma_f32_16x16x32_bf16(pf[qg], onesf, accD[qg], 0, 0, 0);
      }
#pragma unroll
      for (int dt = 0; dt < 4; dt++) {
        int gg = ki * 4 + quad;
        bf16x8 vf = ldfrag(Vts + (dt * 16 + l15) * 128 + (((gg & 8) | ((gg & 7) ^ l7sw)) * 8));
#pragma unroll
        for (int qg = 0; qg < 2; qg++)
          accO[qg][dt] = __builtin_amdgcn_mfma_f32_16x16x32_bf16(pf[qg], vf, accO[qg][dt], 0, 0, 0);
      }
    }
  }
#pragma unroll
  for (int qg = 0; qg < 2; qg++)
#pragma unroll
    for (int r = 0; r < 4; r++) {
      float dinv = 1.0f / accD[qg][r];
      int m = s0 + qg * 64 + wave * 16 + quad * 4 + r;
#pragma unroll
      for (int dt = 0; dt < 4; dt++) {
        size_t idx = (size_t)(b * 2048 + m) * 512 + hh * 64 + dt * 16 + l15;
        attn[idx] = accO[qg][dt][r] * dinv + hres[idx];
      }
    }
}

extern "C" void kernel_launch(void* const* d_in, const int* in_sizes, int n_in,
                              void* d_out, int out_size, void* d_ws, size_t ws_size,
                              hipStream_t stream) {
  (void)in_sizes; (void)n_in; (void)out_size; (void)ws_size;
  const float* x       = (const float*)d_in[0];
  const float* ln_in_g = (const float*)d_in[2];
  const float* ln_in_b = (const float*)d_in[3];
  const float* wq = (const float*)d_in[4];
  const float* bq = (const float*)d_in[5];
  const float* wk = (const float*)d_in[6];
  const float* bk = (const float*)d_in[7];
  const float* wv = (const float*)d_in[8];
  const float* bv = (const float*)d_in[9];
  const float* ln1_g = (const float*)d_in[10];
  const float* ln1_b = (const float*)d_in[11];
  const float* w1 = (const float*)d_in[12];
  const float* b1 = (const float*)d_in[13];
  const float* w2 = (const float*)d_in[14];
  const float* b2 = (const float*)d_in[15];
  const float* ln2_g = (const float*)d_in[16];
  const float* ln2_b = (const float*)d_in[17];

  char* ws = (char*)d_ws;
  size_t off = 0;
  auto alloc = [&](size_t bytes) {
    void* p = ws + off;
    off = (off + bytes + 255) & ~(size_t)255;
    return p;
  };
  u16*   wqkvt = (u16*)  alloc((size_t)1536 * 512 * 2);
  float* bqkv  = (float*)alloc(1536 * 4);
  u16*   w1t   = (u16*)  alloc((size_t)2048 * 512 * 2);
  u16*   w2t   = (u16*)  alloc((size_t)512 * 2048 * 2);
  float* h32   = (float*)alloc((size_t)M_ * 512 * 4);   // hres; later FFN2 kh2+kh3 partials
  u16*   h16   = (u16*)  alloc((size_t)M_ * 512 * 2);   // ln-in bf16 / o16 / FFN2 kh1 partial
  u16*   qkv16 = (u16*)  alloc((size_t)M_ * 1536 * 2);  // + vtb = f16b (FFN mid)
  u16*   vtb   = (u16*)  alloc((size_t)B_ * H_ * 64 * 2048 * 2);  // part of f16b span — never reused!
  float* attn32= (float*)alloc((size_t)M_ * 512 * 4);   // attn out; FFN2 kh0 in-place
  u16*   o16   = h16;
  u16*   f16b  = qkv16;  // 8192*2048*2 bytes spans qkv16+vtb exactly
  // FFN2 bf16 partials: kh1 -> h16 (free after FFN1); kh2/kh3 -> the two
  // halves of h32 (16 MB fp32 hres buffer, free after attn_k). None of
  // these alias f16b (the FFN2 A operand) — that aliasing was the r10 bug.
  u16*   p2b   = (u16*)h32;
  u16*   p3b   = (u16*)h32 + (size_t)M_ * 512;

  prep<<<dim3(2822), 256, 0, stream>>>(wq, wk, wv, w1, w2, bq, bk, bv,
                                       wqkvt, w1t, w2t, bqkv);

  ln_k<true, true, 0><<<M_, 128, 0, stream>>>(x, ln_in_g, ln_in_b, h32, h16,
                                              nullptr, nullptr, nullptr);
  // QKV: M=8192 N=1536 K=512, tile 128x64 -> 24*64 = 1536 blocks
  gemm_db<2, 24, 1, false, false, true, 6><<<dim3(24 * 64), 256, 0, stream>>>(
      h16, wqkvt, bqkv, 512, 1536, nullptr, nullptr, qkv16, nullptr, nullptr);
  vtrans<<<dim3(32, 8, 4), dim3(64, 4), 0, stream>>>(qkv16, vtb);
  attn_k<<<dim3(512), 256, 0, stream>>>(qkv16, vtb, h32, attn32);
  ln_k<false, true, 0><<<M_, 128, 0, stream>>>(attn32, ln1_g, ln1_b, nullptr, o16,
                                               nullptr, nullptr, nullptr);
  // FFN1: M=8192 N=2048 K=512, tile 128x128 -> 16*64 = 1024 blocks
  gemm_db<4, 16, 1, false, false, true, 4><<<dim3(16 * 64), 256, 0, stream>>>(
      o16, w1t, b1, 512, 2048, nullptr, nullptr, f16b, nullptr, nullptr);
  // FFN2: M=8192 N=512 K=2048, tile 128x128, KSPLIT=4 -> 1024 blocks
  gemm_db<4, 4, 4, false, false, false, 4><<<dim3(4 * 4 * 64), 256, 0, stream>>>(
      f16b, w2t, b2, 2048, 512, attn32, attn32, h16, p2b, p3b);
  ln_k<true, false, 3><<<M_, 128, 0, stream>>>(attn32, ln2_g, ln2_b, (float*)d_out,
                                               nullptr, h16, p2b, p3b);
}

// Round 7
// 283.086 us; speedup vs baseline: 1.0848x; 1.0019x over previous
//
#include <hip/hip_runtime.h>
#include <stdint.h>

#define B_ 4
#define S_ 2048
#define D_ 512
#define H_ 8
#define FFN_ 2048
#define M_ (B_*S_)

typedef unsigned short u16;
typedef __attribute__((ext_vector_type(8))) __bf16 bf16x8;
typedef __attribute__((ext_vector_type(8))) u16 u16x8;
typedef __attribute__((ext_vector_type(4))) u16 u16x4;
typedef __attribute__((ext_vector_type(4))) float f32x4;

__device__ __forceinline__ u16 f2bf(float f) {
  uint32_t u = __builtin_bit_cast(uint32_t, f);
  u += 0x7FFFu + ((u >> 16) & 1u);
  return (u16)(u >> 16);
}
__device__ __forceinline__ bf16x8 ldfrag(const u16* p) {
  return __builtin_bit_cast(bf16x8, *(const u16x8*)p);
}
__device__ __forceinline__ void gld16(const void* g, void* l) {
  __builtin_amdgcn_global_load_lds(
      (const __attribute__((address_space(1))) void*)g,
      (__attribute__((address_space(3))) void*)l, 16, 0, 0);
}

// ------- fused weight prep + input layernorm (independent stages) ---------
// ids [0,2816): weight transposes; [2816,2822): bias concat;
// [2822, 2822+4096): input LN, 2 rows per 256-thread block.
__global__ __launch_bounds__(256)
void prep(const float* __restrict__ wq, const float* __restrict__ wk,
          const float* __restrict__ wv, const float* __restrict__ w1,
          const float* __restrict__ w2, const float* __restrict__ bq,
          const float* __restrict__ bk, const float* __restrict__ bv,
          u16* __restrict__ wqkvt, u16* __restrict__ w1t,
          u16* __restrict__ w2t, float* __restrict__ bqkv,
          const float* __restrict__ x, const float* __restrict__ ln_g,
          const float* __restrict__ ln_b, float* __restrict__ h32,
          u16* __restrict__ h16) {
  int id = blockIdx.x, tid = threadIdx.x;
  if (id >= 2822) {  // ---- input LN: rows 2*(id-2822) + (tid>>7) ----
    int row = (id - 2822) * 2 + (tid >> 7);
    int t = tid & 127;
    int rp = tid >> 7, wv2 = (tid >> 6) & 1;
    const float* xr = x + (size_t)row * 512;
    f32x4 v = *(const f32x4*)(xr + t * 4);
    float s = v.x + v.y + v.z + v.w;
    float s2 = v.x*v.x + v.y*v.y + v.z*v.z + v.w*v.w;
#pragma unroll
    for (int m = 32; m; m >>= 1) { s += __shfl_xor(s, m); s2 += __shfl_xor(s2, m); }
    __shared__ float ps[2][2], ps2[2][2];
    if ((tid & 63) == 0) { ps[rp][wv2] = s; ps2[rp][wv2] = s2; }
    __syncthreads();
    s = ps[rp][0] + ps[rp][1]; s2 = ps2[rp][0] + ps2[rp][1];
    float mean = s * (1.f / 512.f);
    float var = s2 * (1.f / 512.f) - mean * mean;
    float rs = rsqrtf(var + 1e-5f);
#pragma unroll
    for (int j = 0; j < 4; j++) {
      float o = (v[j] - mean) * rs * ln_g[t*4 + j] + ln_b[t*4 + j];
      h32[(size_t)row * 512 + t*4 + j] = o;
      h16[(size_t)row * 512 + t*4 + j] = f2bf(o);
    }
    return;
  }
  if (id >= 2816) {  // ---- bias concat ----
    int i = (id - 2816) * 256 + tid;
    bqkv[i] = i < 512 ? bq[i] : (i < 1024 ? bk[i - 512] : bv[i - 1024]);
    return;
  }
  __shared__ float t[32][33];
  const float* W; u16* dst; int K, N, bx, by;
  if (id < 768) {
    int z = id >> 8, r = id & 255;
    W = z == 0 ? wq : (z == 1 ? wk : wv);
    dst = wqkvt + (size_t)z * 512 * 512; K = 512; N = 512;
    bx = r & 15; by = r >> 4;
  } else if (id < 1792) {
    int r = id - 768; W = w1; dst = w1t; K = 512; N = 2048;
    bx = r & 63; by = r >> 6;
  } else {
    int r = id - 1792; W = w2; dst = w2t; K = 2048; N = 512;
    bx = r & 15; by = r >> 4;
  }
  int n0 = bx * 32, k0 = by * 32, x_ = tid & 31, y = tid >> 5;
#pragma unroll
  for (int r = 0; r < 4; r++) t[y + 8*r][x_] = W[(size_t)(k0 + y + 8*r) * N + n0 + x_];
  __syncthreads();
#pragma unroll
  for (int r = 0; r < 4; r++) dst[(size_t)(n0 + y + 8*r) * K + k0 + x_] = f2bf(t[x_][y + 8*r]);
}

// ---------------- layernorm over rows of 512 ------------------------------
// NX = number of bf16 partial arrays to add to x (split-K combine fused)
template <bool OUT32, bool OUT16, int NX>
__global__ __launch_bounds__(128)
void ln_k(const float* __restrict__ x, const float* __restrict__ g,
          const float* __restrict__ bta, float* __restrict__ y32,
          u16* __restrict__ y16, const u16* __restrict__ p1,
          const u16* __restrict__ p2, const u16* __restrict__ p3) {
  int row = blockIdx.x;
  int t = threadIdx.x;
  const float* xr = x + (size_t)row * 512;
  f32x4 v = *(const f32x4*)(xr + t * 4);
  if constexpr (NX >= 1) {
    u16x4 a = *(const u16x4*)(p1 + (size_t)row * 512 + t * 4);
#pragma unroll
    for (int j = 0; j < 4; j++) v[j] += __builtin_bit_cast(float, (uint32_t)a[j] << 16);
  }
  if constexpr (NX >= 2) {
    u16x4 a = *(const u16x4*)(p2 + (size_t)row * 512 + t * 4);
#pragma unroll
    for (int j = 0; j < 4; j++) v[j] += __builtin_bit_cast(float, (uint32_t)a[j] << 16);
  }
  if constexpr (NX >= 3) {
    u16x4 a = *(const u16x4*)(p3 + (size_t)row * 512 + t * 4);
#pragma unroll
    for (int j = 0; j < 4; j++) v[j] += __builtin_bit_cast(float, (uint32_t)a[j] << 16);
  }
  float s = v.x + v.y + v.z + v.w;
  float s2 = v.x*v.x + v.y*v.y + v.z*v.z + v.w*v.w;
#pragma unroll
  for (int m = 32; m; m >>= 1) { s += __shfl_xor(s, m); s2 += __shfl_xor(s2, m); }
  __shared__ float p[4];
  int wv = t >> 6;
  if ((t & 63) == 0) { p[wv] = s; p[2 + wv] = s2; }
  __syncthreads();
  s = p[0] + p[1]; s2 = p[2] + p[3];
  float mean = s * (1.f / 512.f);
  float var = s2 * (1.f / 512.f) - mean * mean;
  float rs = rsqrtf(var + 1e-5f);
#pragma unroll
  for (int j = 0; j < 4; j++) {
    float o = (v[j] - mean) * rs * g[t*4 + j] + bta[t*4 + j];
    if constexpr (OUT32) y32[(size_t)row * 512 + t*4 + j] = o;
    if constexpr (OUT16) y16[(size_t)row * 512 + t*4 + j] = f2bf(o);
  }
}

// ---------------- GEMM: C[M,N] = A[M,K](bf16) @ Wt[N,K]^T + bias ----------
// 2-buffer LDS, ONE __syncthreads per K-iter; operand-swapped MFMA
// (D = bf x af) -> thread owns (m = ...+l15, n = ...+quad*4..+3) -> f32x4/
// u16x4 vectorized epilogue (r6: confirmed win). Split-K (KSPLIT>1):
// kh0 -> fp32+bias+resid in-place; kh>=1 -> bf16 partial to C16/C16b/C16c
// (combined in ln_k<NX>). r7: FFN2 KSPLIT 4->2 -- C0 (per-block epilogue
// overhead, the measured ~33-50% cost at 16 iters) amortizes over 32 iters,
// and partial write traffic drops 24->8 MB (+16 MB fewer ln2 reads).
// Partial buffers MUST NOT alias the A operand (r10 bug).
// LDS swizzle: granule c of row r stored at c ^ ((r>>1)&3).
// 1-D grid, XCD-aware raster keeps each A row-stripe in one XCD's L2.
template <int NTW, int NCOL, int KSPLIT, bool RESID, bool OUT32, bool OUT16, int MINW>
__global__ __launch_bounds__(256, MINW)
void gemm_db(const u16* __restrict__ A, const u16* __restrict__ Bt,
             const float* __restrict__ bias, int K, int N,
             const float* resid, float* C32, u16* __restrict__ C16,
             u16* __restrict__ C16b, u16* __restrict__ C16c) {
  __shared__ __align__(16) u16 As[2][128 * 32];
  __shared__ __align__(16) u16 Bs[2][NTW * 1024];
  const int tid = threadIdx.x;
  const int wave = tid >> 6, lane = tid & 63;
  const int l15 = lane & 15, quad = lane >> 4;
  const int wm = wave >> 1, wn = wave & 1;

  int lin = blockIdx.x;
  int kh = 0;
  if constexpr (KSPLIT > 1) {
    const int nblk = (M_ / 128) * NCOL;
    kh = lin / nblk;
    lin -= kh * nblk;
  }
  const int rpx = (M_ / 128) / 8;              // row tiles per XCD
  const int xcd = lin & 7, local = lin >> 3;
  const int row0 = (xcd * rpx + local / NCOL) * 128;
  const int col0 = (local % NCOL) * (NTW * 32);
  const int klen = K / KSPLIT;
  const int kstart = kh * klen;

  f32x4 acc[4][NTW];
#pragma unroll
  for (int i = 0; i < 4; i++)
#pragma unroll
    for (int j = 0; j < NTW; j++) acc[i][j] = (f32x4){0.f, 0.f, 0.f, 0.f};

  const int lr = lane >> 2;
  const int lc = ((lane & 3) ^ ((lane >> 3) & 3)) * 8;  // swizzled source granule
  const u16* aG0 = A + (size_t)(row0 + (wave * 2) * 16 + lr) * K + lc;
  const u16* aG1 = A + (size_t)(row0 + (wave * 2 + 1) * 16 + lr) * K + lc;
  const int aO0 = (wave * 2) * 512 + lane * 8;
  const int aO1 = (wave * 2 + 1) * 512 + lane * 8;
  const u16* bG[NTW / 2];
  int bO[NTW / 2];
#pragma unroll
  for (int i = 0; i < NTW / 2; i++) {
    int ch = wave * (NTW / 2) + i;
    bG[i] = Bt + (size_t)(col0 + ch * 16 + lr) * K + lc;
    bO[i] = ch * 512 + lane * 8;
  }
  const int rsw = (l15 >> 1) & 3;  // frag-read swizzle term

  auto issue = [&](int kof, int buf) {
    gld16(aG0 + kof, &As[buf][aO0]);
    gld16(aG1 + kof, &As[buf][aO1]);
#pragma unroll
    for (int i = 0; i < NTW / 2; i++) gld16(bG[i] + kof, &Bs[buf][bO[i]]);
  };

  const int nIter = klen >> 5;
  issue(kstart, 0);
  __syncthreads();

  for (int it = 0; it < nIter; it++) {
    const int cur = it & 1;
    if (it + 1 < nIter) issue(kstart + ((it + 1) << 5), cur ^ 1);
    bf16x8 af[4], bf[NTW];
#pragma unroll
    for (int mt = 0; mt < 4; mt++)
      af[mt] = ldfrag(&As[cur][(wm * 64 + mt * 16 + l15) * 32 + ((quad ^ rsw) * 8)]);
#pragma unroll
    for (int nt = 0; nt < NTW; nt++)
      bf[nt] = ldfrag(&Bs[cur][(wn * (NTW * 16) + nt * 16 + l15) * 32 + ((quad ^ rsw) * 8)]);
    // operand-swapped: D = bf x af -> m on l15, n on quad*4+r (see header)
#pragma unroll
    for (int mt = 0; mt < 4; mt++)
#pragma unroll
      for (int nt = 0; nt < NTW; nt++)
        acc[mt][nt] = __builtin_amdgcn_mfma_f32_16x16x32_bf16(bf[nt], af[mt], acc[mt][nt], 0, 0, 0);
    __syncthreads();
  }

  // vectorized epilogue: thread owns (m = ...+l15, n = ...+quad*4 .. +3)
#pragma unroll
  for (int mt = 0; mt < 4; mt++)
#pragma unroll
    for (int nt = 0; nt < NTW; nt++) {
      const int m = row0 + wm * 64 + mt * 16 + l15;
      const int n = col0 + wn * (NTW * 16) + nt * 16 + quad * 4;
      const size_t idx = (size_t)m * N + n;
      f32x4 v4 = acc[mt][nt];
      if (kh == 0) {
        const f32x4 b4 = *(const f32x4*)(bias + n);
#pragma unroll
        for (int r = 0; r < 4; r++) v4[r] += b4[r];
      }
      if constexpr (KSPLIT > 1) {
        if (kh == 0) {
          const f32x4 rs = *(const f32x4*)(resid + idx);
#pragma unroll
          for (int r = 0; r < 4; r++) v4[r] += rs[r];
          *(f32x4*)(C32 + idx) = v4;
        } else {
          u16x4 o;
#pragma unroll
          for (int r = 0; r < 4; r++) o[r] = f2bf(v4[r]);
          u16* dst = kh == 1 ? C16 : (kh == 2 ? C16b : C16c);
          *(u16x4*)(dst + idx) = o;
        }
      } else {
        if constexpr (RESID) {
          const f32x4 rs = *(const f32x4*)(resid + idx);
#pragma unroll
          for (int r = 0; r < 4; r++) v4[r] += rs[r];
        }
        if constexpr (OUT32) *(f32x4*)(C32 + idx) = v4;
        if constexpr (OUT16) {
          u16x4 o;
#pragma unroll
          for (int r = 0; r < 4; r++) o[r] = f2bf(v4[r]);
          *(u16x4*)(C16 + idx) = o;
        }
      }
    }
}

// ---------------- transpose V head-wise: vt[b,h,d,s] ----------------------
__global__ __launch_bounds__(256)
void vtrans(const u16* __restrict__ qkv, u16* __restrict__ vt) {
  __shared__ u16 t[64][65];
  int s0 = blockIdx.x * 64, h = blockIdx.y, b = blockIdx.z;
  int x = threadIdx.x, y = threadIdx.y;  // (64,4)
  const u16* src = qkv + (size_t)(b * 2048 + s0) * 1536 + 1024 + h * 64;
#pragma unroll
  for (int r = 0; r < 16; r++) { int s = y + 4*r; t[s][x] = src[(size_t)s * 1536 + x]; }
  __syncthreads();
  u16* dst = vt + (size_t)((b * 8 + h) * 64) * 2048 + s0;
#pragma unroll
  for (int r = 0; r < 16; r++) { int d = y + 4*r; dst[(size_t)d * 2048 + x] = t[x][d]; }
}

// ---------------- attention: block = (b, h, 128 q-rows) -------------------
#define PSTR 136
__global__ __launch_bounds__(256)
void attn_k(const u16* __restrict__ qkv, const u16* __restrict__ vt,
            const float* __restrict__ hres, float* __restrict__ attn) {
  __shared__ __align__(16) u16 smem[8192 + 8192 + 128 * PSTR];
  u16* Ks = smem;
  u16* Vts = smem + 8192;
  u16* Ps = smem + 16384;
  u16* Qs = Ps;

  const int lin = blockIdx.x;
  const int xcd = lin & 7, g = lin >> 3;
  const int c = g & 15;                 // 128-row q chunk
  const int bh = xcd * 4 + (g >> 4);    // (b,h) pinned to xcd
  const int hh = bh & 7, b = bh >> 3;
  const int s0 = c * 128;
  const int tid = threadIdx.x, wave = tid >> 6, lane = tid & 63;
  const int l15 = lane & 15, quad = lane >> 4;
  const int t_lo = (c > 4) ? c - 4 : 0;
  const int t_hi = (c + 2 < 16) ? c + 2 : 16;
  const int l7sw = l15 & 7;

  // stage Q (128x64), swizzled
  {
    const int cg = ((lane & 7) ^ (lane >> 3)) * 8;
    const int cp = (lane & 7) * 8;
#pragma unroll
    for (int q2 = 0; q2 < 4; q2++) {
      int r = wave * 32 + q2 * 8 + (lane >> 3);
      gld16(qkv + (size_t)(b * 2048 + s0 + r) * 1536 + hh * 64 + cg, Qs + r * 64 + cp);
    }
  }
  __syncthreads();
  bf16x8 qf[2][2];
#pragma unroll
  for (int qg = 0; qg < 2; qg++)
#pragma unroll
    for (int f = 0; f < 2; f++)
      qf[qg][f] = ldfrag(Qs + (qg * 64 + wave * 16 + l15) * 64 + (((f * 4 + quad) ^ l7sw) * 8));

  const u16x8 ones16 = {0x3F80, 0x3F80, 0x3F80, 0x3F80, 0x3F80, 0x3F80, 0x3F80, 0x3F80};
  const bf16x8 onesf = __builtin_bit_cast(bf16x8, ones16);

  f32x4 accO[2][4];
#pragma unroll
  for (int qg = 0; qg < 2; qg++)
#pragma unroll
    for (int i = 0; i < 4; i++) accO[qg][i] = (f32x4){0.f, 0.f, 0.f, 0.f};
  f32x4 accD[2] = {(f32x4){0.f, 0.f, 0.f, 0.f}, (f32x4){0.f, 0.f, 0.f, 0.f}};

  for (int kt = t_lo; kt < t_hi; ++kt) {
    __syncthreads();  // prior-iter reads done before restage
    {
      const int cgk = ((lane & 7) ^ (lane >> 3)) * 8;
      const int cpk = (lane & 7) * 8;
#pragma unroll
      for (int q2 = 0; q2 < 4; q2++) {  // K tile 128 rows
        int r = wave * 32 + q2 * 8 + (lane >> 3);
        gld16(qkv + (size_t)(b * 2048 + kt * 128 + r) * 1536 + 512 + hh * 64 + cgk,
              Ks + r * 64 + cpk);
      }
      const int cpv = (lane & 15) * 8;
#pragma unroll
      for (int q2 = 0; q2 < 4; q2++) {  // Vt tile 64 rows
        int d = (wave * 4 + q2) * 4 + (lane >> 4);
        int cgv = ((lane & 8) | ((lane & 7) ^ (lane >> 4) ^ ((q2 & 1) << 2))) * 8;
        gld16(vt + (size_t)((b * 8 + hh) * 64 + d) * 2048 + kt * 128 + cgv,
              Vts + d * 128 + cpv);
      }
    }
    __syncthreads();

#pragma unroll
    for (int nt = 0; nt < 8; nt++) {
      bf16x8 kf0 = ldfrag(Ks + (nt * 16 + l15) * 64 + ((quad ^ l7sw) * 8));
      bf16x8 kf1 = ldfrag(Ks + (nt * 16 + l15) * 64 + (((4 + quad) ^ l7sw) * 8));
#pragma unroll
      for (int qg = 0; qg < 2; qg++) {
        f32x4 s4 = (f32x4){0.f, 0.f, 0.f, 0.f};
        s4 = __builtin_amdgcn_mfma_f32_16x16x32_bf16(qf[qg][0], kf0, s4, 0, 0, 0);
        s4 = __builtin_amdgcn_mfma_f32_16x16x32_bf16(qf[qg][1], kf1, s4, 0, 0, 0);
#pragma unroll
        for (int r = 0; r < 4; r++) {
          float pp = exp2f(s4[r] * (1.4426950408889634f * 0.125f));  // exp(s/8)
          Ps[(qg * 64 + wave * 16 + quad * 4 + r) * PSTR + nt * 16 + l15] =
              (u16)(__builtin_bit_cast(uint32_t, pp) >> 16);  // truncate
        }
      }
    }
    // PV — wave reads only its own P rows, no cross-wave barrier needed
#pragma unroll
    for (int ki = 0; ki < 4; ki++) {
      bf16x8 pf[2];
#pragma unroll
      for (int qg = 0; qg < 2; qg++) {
        pf[qg] = ldfrag(Ps + (qg * 64 + wave * 16 + l15) * PSTR + (ki * 4 + quad) * 8);
        accD[qg] = __builtin_amdgcn_mfma_f32_16x16x32_bf16(pf[qg], onesf, accD[qg], 0, 0, 0);
      }
#pragma unroll
      for (int dt = 0; dt < 4; dt++) {
        int gg = ki * 4 + quad;
        bf16x8 vf = ldfrag(Vts + (dt * 16 + l15) * 128 + (((gg & 8) | ((gg & 7) ^ l7sw)) * 8));
#pragma unroll
        for (int qg = 0; qg < 2; qg++)
          accO[qg][dt] = __builtin_amdgcn_mfma_f32_16x16x32_bf16(pf[qg], vf, accO[qg][dt], 0, 0, 0);
      }
    }
  }
#pragma unroll
  for (int qg = 0; qg < 2; qg++)
#pragma unroll
    for (int r = 0; r < 4; r++) {
      float dinv = 1.0f / accD[qg][r];
      int m = s0 + qg * 64 + wave * 16 + quad * 4 + r;
#pragma unroll
      for (int dt = 0; dt < 4; dt++) {
        size_t idx = (size_t)(b * 2048 + m) * 512 + hh * 64 + dt * 16 + l15;
        attn[idx] = accO[qg][dt][r] * dinv + hres[idx];
      }
    }
}

extern "C" void kernel_launch(void* const* d_in, const int* in_sizes, int n_in,
                              void* d_out, int out_size, void* d_ws, size_t ws_size,
                              hipStream_t stream) {
  (void)in_sizes; (void)n_in; (void)out_size; (void)ws_size;
  const float* x       = (const float*)d_in[0];
  const float* ln_in_g = (const float*)d_in[2];
  const float* ln_in_b = (const float*)d_in[3];
  const float* wq = (const float*)d_in[4];
  const float* bq = (const float*)d_in[5];
  const float* wk = (const float*)d_in[6];
  const float* bk = (const float*)d_in[7];
  const float* wv = (const float*)d_in[8];
  const float* bv = (const float*)d_in[9];
  const float* ln1_g = (const float*)d_in[10];
  const float* ln1_b = (const float*)d_in[11];
  const float* w1 = (const float*)d_in[12];
  const float* b1 = (const float*)d_in[13];
  const float* w2 = (const float*)d_in[14];
  const float* b2 = (const float*)d_in[15];
  const float* ln2_g = (const float*)d_in[16];
  const float* ln2_b = (const float*)d_in[17];

  char* ws = (char*)d_ws;
  size_t off = 0;
  auto alloc = [&](size_t bytes) {
    void* p = ws + off;
    off = (off + bytes + 255) & ~(size_t)255;
    return p;
  };
  u16*   wqkvt = (u16*)  alloc((size_t)1536 * 512 * 2);
  float* bqkv  = (float*)alloc(1536 * 4);
  u16*   w1t   = (u16*)  alloc((size_t)2048 * 512 * 2);
  u16*   w2t   = (u16*)  alloc((size_t)512 * 2048 * 2);
  float* h32   = (float*)alloc((size_t)M_ * 512 * 4);   // hres
  u16*   h16   = (u16*)  alloc((size_t)M_ * 512 * 2);   // ln-in bf16 / o16 / FFN2 kh1 partial
  u16*   qkv16 = (u16*)  alloc((size_t)M_ * 1536 * 2);  // + vtb = f16b (FFN mid)
  u16*   vtb   = (u16*)  alloc((size_t)B_ * H_ * 64 * 2048 * 2);  // part of f16b span — never reused!
  float* attn32= (float*)alloc((size_t)M_ * 512 * 4);   // attn out; FFN2 kh0 in-place
  u16*   o16   = h16;
  u16*   f16b  = qkv16;  // 8192*2048*2 bytes spans qkv16+vtb exactly
  // FFN2 bf16 partial (KSPLIT=2): kh1 -> h16 (free after FFN1 reads it as
  // A; FFN2 runs after FFN1 completes). Does NOT alias f16b (r10 rule).
  u16*   p1b   = h16;

  prep<<<dim3(2822 + 4096), 256, 0, stream>>>(wq, wk, wv, w1, w2, bq, bk, bv,
                                              wqkvt, w1t, w2t, bqkv,
                                              x, ln_in_g, ln_in_b, h32, h16);

  // QKV: M=8192 N=1536 K=512, tile 128x64 -> 24*64 = 1536 blocks
  gemm_db<2, 24, 1, false, false, true, 6><<<dim3(24 * 64), 256, 0, stream>>>(
      h16, wqkvt, bqkv, 512, 1536, nullptr, nullptr, qkv16, nullptr, nullptr);
  vtrans<<<dim3(32, 8, 4), dim3(64, 4), 0, stream>>>(qkv16, vtb);
  attn_k<<<dim3(512), 256, 0, stream>>>(qkv16, vtb, h32, attn32);
  ln_k<false, true, 0><<<M_, 128, 0, stream>>>(attn32, ln1_g, ln1_b, nullptr, o16,
                                               nullptr, nullptr, nullptr);
  // FFN1: M=8192 N=2048 K=512, tile 128x128 -> 16*64 = 1024 blocks
  gemm_db<4, 16, 1, false, false, true, 4><<<dim3(16 * 64), 256, 0, stream>>>(
      o16, w1t, b1, 512, 2048, nullptr, nullptr, f16b, nullptr, nullptr);
  // FFN2: M=8192 N=512 K=2048, tile 128x64, KSPLIT=2 -> 2*8*64 = 1024 blocks
  gemm_db<2, 8, 2, false, false, false, 6><<<dim3(2 * 8 * 64), 256, 0, stream>>>(
      f16b, w2t, b2, 2048, 512, attn32, attn32, p1b, nullptr, nullptr);
  ln_k<true, false, 1><<<M_, 128, 0, stream>>>(attn32, ln2_g, ln2_b, (float*)d_out,
                                               nullptr, p1b, nullptr, nullptr);
}